// Round 7
// baseline (322.295 us; speedup 1.0000x reference)
//
#include <hip/hip_runtime.h>
#include <hip/hip_bf16.h>

// EncoderLayer: N=4, L=1024, H=1024, HEADS=16, HS=64, FFN=4096
// fp32 in/out. GEMMs + attention via bf16 MFMA (16x16x32), fp32 accumulate.
// QKV, FFN1, FFN2 use the 256^2 2-bar-per-K-tile counted-vmcnt GEMM.
//   Round 7: dropped the explicit lgkmcnt(0) before the MFMA clusters --
//   the compiler emits fine-grained lgkmcnt(N) per MFMA operand, letting
//   the ds_read burst hide under the MFMA cluster (the explicit drain was
//   serializing reads vs compute; see round-6 postmortem arithmetic).
//   The lgkmcnt(0) before BAR#1 remains: it is the WAR fence for buf reuse.
//   FFN2 runs split-K=4 (grid 4x16x4, Kh=1024) writing BF16 partials.
// Wo remains 128^2 split-K=2 with fp32 partials.
// Attention v2: QBLK=128, K/V via global_load_lds into XOR-swizzled LDS,
//   double-buffered counted vmcnt(4); Q in registers; setprio on MFMA.
// prep_all: one dispatch = 6 weight transposes + x->bf16 + bias concat.
//
// Workspace (<= ~121 MB):
//   [0,32M)    Wo partials p0,p1 (fp32 16MB ea) -> later FFN2 bf16 partials
//              pb[4] (8MB ea, contiguous); qkvb bf16 [0,24M) pre-attn;
//              vtb bf16 [24,32M) attention-time.
//   [32,48M)   x1 fp32
//   [48,56M)   x1b bf16
//   [56,64M)   ctxb bf16
//   [64,96M)   hb bf16 [4096][4096]; xb bf16 lives here pre-FFN1
//   [96,102M)  Wqkvt bf16, [102,104M) Wot, [104,112M) W1t, [112,120M) W2t
//   [120M,..)  bias_qkv fp32 [3072]

#define HDIM 1024
#define FDIM 4096
#define ROWS 4096
#define NHEAD 16
#define HS 64
#define SEQ 1024
#define NBATCH 4
#define PD 40

typedef unsigned short ushort_t;
typedef short short8 __attribute__((ext_vector_type(8)));
typedef float f32x4 __attribute__((ext_vector_type(4)));

__device__ __forceinline__ ushort_t f2bf(float v) {
  union { float f; unsigned int u; } c; c.f = v;
  unsigned int u = c.u;
  u += 0x7fffu + ((u >> 16) & 1u);
  return (ushort_t)(u >> 16);
}

__device__ __forceinline__ float bf2f(ushort_t u) {
  union { unsigned int u; float f; } c;
  c.u = ((unsigned int)u) << 16;
  return c.f;
}

__device__ __forceinline__ void gld_lds16(ushort_t* lds, const ushort_t* g) {
  __builtin_amdgcn_global_load_lds(
      (const __attribute__((address_space(1))) unsigned int*)g,
      (__attribute__((address_space(3))) unsigned int*)lds, 16, 0, 0);
}

// ---------------- prep: 6 weight transposes + x->bf16 + bias concat -------
// grid (128, 32, 8). z 0..3: Wq,Wk,Wv,Wo (bx<32); z=4: W1; z=5: W2;
// z=6: x fp32 -> xb bf16; z=7: concat biases.
__global__ __launch_bounds__(256) void prep_all(const float* __restrict__ s0,
                                                const float* __restrict__ s1,
                                                const float* __restrict__ s2,
                                                const float* __restrict__ s3,
                                                const float* __restrict__ s4,
                                                const float* __restrict__ s5,
                                                ushort_t* __restrict__ dqkv,
                                                ushort_t* __restrict__ dot,
                                                ushort_t* __restrict__ d1,
                                                ushort_t* __restrict__ d2,
                                                const float* __restrict__ x,
                                                ushort_t* __restrict__ xb,
                                                const float* __restrict__ ba,
                                                const float* __restrict__ bb,
                                                const float* __restrict__ bc,
                                                float* __restrict__ bqkv) {
  const int z = blockIdx.z;
  if (z == 6) {
    int i = (blockIdx.y * 128 + blockIdx.x) * 256 + threadIdx.x;  // < 1M float4s
    float4 v = ((const float4*)x)[i];
    ushort4 o;
    o.x = f2bf(v.x); o.y = f2bf(v.y); o.z = f2bf(v.z); o.w = f2bf(v.w);
    ((ushort4*)xb)[i] = o;
    return;
  }
  if (z == 7) {
    if (blockIdx.y != 0 || blockIdx.x >= 12) return;
    int i = blockIdx.x * 256 + threadIdx.x;
    float v = (i < 1024) ? ba[i] : (i < 2048 ? bb[i - 1024] : bc[i - 2048]);
    bqkv[i] = v;
    return;
  }
  __shared__ float t[32][33];
  const float* src;
  ushort_t* dst;
  int K, N, n0, k0;
  if (z < 4) {
    if (blockIdx.x >= 32) return;
    src = (z == 0) ? s0 : (z == 1) ? s1 : (z == 2) ? s2 : s3;
    dst = (z < 3) ? (dqkv + (size_t)z * 1024 * 1024) : dot;
    K = 1024; N = 1024; n0 = blockIdx.x * 32; k0 = blockIdx.y * 32;
  } else if (z == 4) {
    src = s4; dst = d1; K = 1024; N = 4096;
    n0 = blockIdx.x * 32; k0 = blockIdx.y * 32;
  } else {
    src = s5; dst = d2; K = 4096; N = 1024;
    n0 = blockIdx.y * 32; k0 = blockIdx.x * 32;
  }
  int c = threadIdx.x & 31, r0 = (threadIdx.x >> 5) * 4;
#pragma unroll
  for (int i = 0; i < 4; ++i)
    t[r0 + i][c] = src[(size_t)(k0 + r0 + i) * N + n0 + c];
  __syncthreads();
#pragma unroll
  for (int i = 0; i < 4; ++i)
    dst[(size_t)(n0 + r0 + i) * K + k0 + c] = f2bf(t[c][r0 + i]);
}

__global__ __launch_bounds__(256) void vtrans_k(const ushort_t* __restrict__ qkvb,
                                                ushort_t* __restrict__ vtb) {
  __shared__ ushort_t t[32][33];
  int t0 = blockIdx.x * 32, d0 = blockIdx.y * 32, nh = blockIdx.z;
  int n = nh >> 4, h = nh & 15;
  int c = threadIdx.x & 31, r0 = (threadIdx.x >> 5) * 4;
#pragma unroll
  for (int i = 0; i < 4; ++i)
    t[r0 + i][c] = qkvb[(size_t)(n * SEQ + t0 + r0 + i) * 3072 + 2048 + h * 64 + d0 + c];
  __syncthreads();
#pragma unroll
  for (int i = 0; i < 4; ++i)
    vtb[(size_t)(nh * 64 + d0 + r0 + i) * SEQ + t0 + c] = t[c][r0 + i];
}

// ---------------- 128^2 MFMA GEMM (kept for Wo split-K=2) -----------------
template<bool RELU, bool OUT_F32, bool OUT_BF16, int SPLITK>
__global__ __launch_bounds__(256) void gemm_mfma(const ushort_t* __restrict__ A,
                                                 const ushort_t* __restrict__ Bt,
                                                 const float* __restrict__ bias,
                                                 float* __restrict__ Cf,
                                                 ushort_t* __restrict__ Cb,
                                                 int M, int N, int K) {
  __shared__ __align__(16) ushort_t As[128 * 32];
  __shared__ __align__(16) ushort_t Bs[128 * 32];
  const int tid = threadIdx.x;
  const int w = tid >> 6, l = tid & 63;
  const int lane16 = l & 15, quad = l >> 4;
  const int wm = w & 1, wn = w >> 1;

  const int flat = blockIdx.y * gridDim.x + blockIdx.x;
  const int per = (gridDim.x * gridDim.y) >> 3;
  const int nf = (flat & 7) * per + (flat >> 3);
  const int bx = nf % gridDim.x;
  const int by = nf / gridDim.x;

  const int row0 = by * 128, col0 = bx * 128;
  const int z = (SPLITK > 1) ? blockIdx.z : 0;
  const int Kh = K / SPLITK;
  const int kbeg = z * Kh;

  const ushort_t* Ag = A + (size_t)row0 * K;
  const ushort_t* Bg = Bt + (size_t)col0 * K;

  f32x4 acc[4][4] = {};
  const int fr = tid >> 2;
  const int fc = (tid & 3) << 3;

  for (int kt = kbeg; kt < kbeg + Kh; kt += 32) {
#pragma unroll
    for (int rnd = 0; rnd < 2; ++rnd) {
      int r = fr + rnd * 64;
      ushort_t* ldsA = &As[(size_t)(rnd * 256 + w * 64) * 8];
      ushort_t* ldsB = &Bs[(size_t)(rnd * 256 + w * 64) * 8];
      gld_lds16(ldsA, Ag + (size_t)r * K + kt + fc);
      gld_lds16(ldsB, Bg + (size_t)r * K + kt + fc);
    }
    __syncthreads();
    short8 af[4], bfr[4];
#pragma unroll
    for (int i = 0; i < 4; ++i) {
      af[i]  = *(const short8*)&As[(wm * 64 + i * 16 + lane16) * 32 + quad * 8];
      bfr[i] = *(const short8*)&Bs[(wn * 64 + i * 16 + lane16) * 32 + quad * 8];
    }
#pragma unroll
    for (int mi = 0; mi < 4; ++mi)
#pragma unroll
      for (int ni = 0; ni < 4; ++ni)
        acc[mi][ni] = __builtin_amdgcn_mfma_f32_16x16x32_bf16(
            af[mi], bfr[ni], acc[mi][ni], 0, 0, 0);
    __syncthreads();
  }

  float* Cp = (SPLITK > 1) ? (Cf + (size_t)z * M * N) : Cf;
#pragma unroll
  for (int mi = 0; mi < 4; ++mi) {
    int gr = row0 + wm * 64 + mi * 16 + quad * 4;
#pragma unroll
    for (int ni = 0; ni < 4; ++ni) {
      int gc = col0 + wn * 64 + ni * 16 + lane16;
      float bs = (SPLITK > 1) ? 0.0f : bias[gc];
#pragma unroll
      for (int r = 0; r < 4; ++r) {
        float v = acc[mi][ni][r] + bs;
        if (RELU) v = fmaxf(v, 0.0f);
        size_t idx = (size_t)(gr + r) * N + gc;
        if constexpr (OUT_F32) Cp[idx] = v;
        if constexpr (OUT_BF16) Cb[idx] = f2bf(v);
      }
    }
  }
}

// ---------------- 256^2 2-barrier-per-tile counted-vmcnt GEMM -------------
// C = A(MxK,bf16) @ Bt(NxK,bf16)^T [+ bias] [, ReLU].
// PBF16: bf16 partials (no bias) to Cb + z*M*N; else bf16+bias to Cb.
// 8 waves (2Mx4N), XOR-swizzled LDS, pre-swizzled global_load_lds source.
// One phase per K-tile t (buf b = t&1, prefetch s = min(t+2, last)):
//   LD half1 (A mb0 k0k1 + B k0k1, 16 ds_reads)
//   MFMA32 (acc[0..3])   <- NO explicit lgkm drain: compiler emits partial
//                           lgkmcnt(N) per operand -> reads hide under MFMA
//   LD half2 (A mb4 k0k1, 8 ds_reads, reusing frag regs)
//   lgkmcnt(0); BAR#1    <- WAR fence: all reads of buf[b] drained
//   STAGE tile s -> buf[b] (8 gld)
//   MFMA32 (acc[4..7]); vmcnt(8)  <- drains tile t+1's 8 stages, leaves
//          tile s's 8 in flight; never 0
//   BAR#2   <- publishes buf[b^1] = tile t+1 for the next phase
// Steady state: 16 outstanding after stage, 8 after vmcnt. Prologue stages
// tiles 0,1 (16 loads), vmcnt(8) drains tile 0. Tail clamps s to last:
// junk stages overwrite only the currently-dying buffer after BAR#1.
template<bool RELU, bool PBF16, int SPLITK>
__global__ __launch_bounds__(512, 2) void gemm256(const ushort_t* __restrict__ A,
                                                  const ushort_t* __restrict__ Bt,
                                                  const float* __restrict__ bias,
                                                  ushort_t* __restrict__ Cb,
                                                  int M, int N, int K) {
  __shared__ __align__(16) ushort_t sA[2][16384];
  __shared__ __align__(16) ushort_t sB[2][16384];
  const int tid = threadIdx.x;
  const int w = tid >> 6, l = tid & 63;
  const int lane16 = l & 15, quad = l >> 4;
  const int wm = w >> 2, wn = w & 3;

  const int gx = gridDim.x;
  const int flat = blockIdx.y * gx + blockIdx.x;
  const int per = (gx * gridDim.y) >> 3;
  const int nf = (flat & 7) * per + (flat >> 3);
  const int bx = nf % gx, by = nf / gx;
  const int row0 = by * 256, col0 = bx * 256;

  const int z = (SPLITK > 1) ? blockIdx.z : 0;
  const int Kh = K / SPLITK;
  const int kbeg = z * Kh;

  const ushort_t* Ag = A + (size_t)row0 * K + kbeg;
  const ushort_t* Bg = Bt + (size_t)col0 * K + kbeg;

  const int lr8 = l >> 3, lsl = l & 7;
  const size_t stg = (size_t)(w * 8 + lr8) * K + (size_t)((lsl ^ lr8) << 3);
  const int wslab = w * 512;

  const int rowA = (wm * 128 + lane16) * 64;
  const int rowB = (wn * 64 + lane16) * 64;
  const int sl0 = (quad ^ (lane16 & 7)) * 8;

  f32x4 acc[8][4] = {};
  short8 a0[4], a1[4], b0[4], b1[4];

#define STAGE_A(bf, t, q) gld_lds16(&sA[bf][(q) * 4096 + wslab], \
    Ag + stg + (size_t)(q) * 64 * (size_t)K + (size_t)(t) * 64)
#define STAGE_B(bf, t, q) gld_lds16(&sB[bf][(q) * 4096 + wslab], \
    Bg + stg + (size_t)(q) * 64 * (size_t)K + (size_t)(t) * 64)
#define STAGE_ALL(bf, t) { \
    STAGE_A(bf, t, 0); STAGE_A(bf, t, 1); STAGE_A(bf, t, 2); STAGE_A(bf, t, 3); \
    STAGE_B(bf, t, 0); STAGE_B(bf, t, 1); STAGE_B(bf, t, 2); STAGE_B(bf, t, 3); }
#define LDA(bf, mi, ks) (*(const short8*)&sA[bf][rowA + (mi) * 1024 + (sl0 ^ ((ks) * 32))])
#define LDB(bf, ni, ks) (*(const short8*)&sB[bf][rowB + (ni) * 1024 + (sl0 ^ ((ks) * 32))])
#define LD_A2(bf, mb) { \
    a0[0] = LDA(bf, (mb) + 0, 0); a0[1] = LDA(bf, (mb) + 1, 0); \
    a0[2] = LDA(bf, (mb) + 2, 0); a0[3] = LDA(bf, (mb) + 3, 0); \
    a1[0] = LDA(bf, (mb) + 0, 1); a1[1] = LDA(bf, (mb) + 1, 1); \
    a1[2] = LDA(bf, (mb) + 2, 1); a1[3] = LDA(bf, (mb) + 3, 1); }
#define LD_B2(bf) { \
    b0[0] = LDB(bf, 0, 0); b0[1] = LDB(bf, 1, 0); \
    b0[2] = LDB(bf, 2, 0); b0[3] = LDB(bf, 3, 0); \
    b1[0] = LDB(bf, 0, 1); b1[1] = LDB(bf, 1, 1); \
    b1[2] = LDB(bf, 2, 1); b1[3] = LDB(bf, 3, 1); }
#define MFMA32(MB) { \
    _Pragma("unroll") for (int mi = 0; mi < 4; ++mi) { \
      _Pragma("unroll") for (int ni = 0; ni < 4; ++ni) \
        acc[(MB) + mi][ni] = __builtin_amdgcn_mfma_f32_16x16x32_bf16( \
            a0[mi], b0[ni], acc[(MB) + mi][ni], 0, 0, 0); \
    } \
    _Pragma("unroll") for (int mi = 0; mi < 4; ++mi) { \
      _Pragma("unroll") for (int ni = 0; ni < 4; ++ni) \
        acc[(MB) + mi][ni] = __builtin_amdgcn_mfma_f32_16x16x32_bf16( \
            a1[mi], b1[ni], acc[(MB) + mi][ni], 0, 0, 0); \
    } }
#define BAR() __builtin_amdgcn_s_barrier()
#define WAIT_LGKM() asm volatile("s_waitcnt lgkmcnt(0)" ::: "memory")
#define WAIT_VM8() asm volatile("s_waitcnt vmcnt(8)" ::: "memory")

  // prologue: tile0 -> buf0, tile1 -> buf1 (8 loads each)
  STAGE_ALL(0, 0);
  STAGE_ALL(1, 1);
  WAIT_VM8();   // tile0's 8 landed; tile1's 8 in flight
  BAR();

  const int last = (Kh >> 6) - 1;
  const int nt = Kh >> 6;  // Kh multiple of 128 -> nt even, >= 2
  for (int t = 0; t < nt; ++t) {
    const int b = t & 1;
    int s = t + 2;
    if (s > last) s = last;

    // half1: A mb0 (both k-halves) + B (both k-halves); no explicit drain --
    // compiler inserts per-operand lgkmcnt(N), overlapping reads with MFMA
    LD_A2(b, 0); LD_B2(b);
    __builtin_amdgcn_s_setprio(1); MFMA32(0); __builtin_amdgcn_s_setprio(0);
    // half2: A mb4 into the same frag regs (b0/b1 reused as-is)
    LD_A2(b, 4);
    WAIT_LGKM();               // WAR fence: this wave's buf[b] reads drained
    BAR();                     // all waves' reads of buf[b] complete
    STAGE_ALL(b, s);           // overwrite buf[b] with tile s
    __builtin_amdgcn_s_setprio(1); MFMA32(4); __builtin_amdgcn_s_setprio(0);
    WAIT_VM8();                // tile t+1 fully landed in buf[b^1]
    BAR();                     // publish
  }

#undef STAGE_A
#undef STAGE_B
#undef STAGE_ALL
#undef LDA
#undef LDB
#undef LD_A2
#undef LD_B2
#undef MFMA32
#undef BAR
#undef WAIT_LGKM
#undef WAIT_VM8

  if constexpr (PBF16) {
    ushort_t* Cp = Cb + (size_t)z * M * N;
#pragma unroll
    for (int mi = 0; mi < 8; ++mi) {
      const int gr = row0 + wm * 128 + mi * 16 + quad * 4;
#pragma unroll
      for (int ni = 0; ni < 4; ++ni) {
        const int gc = col0 + wn * 64 + ni * 16 + lane16;
#pragma unroll
        for (int r = 0; r < 4; ++r)
          Cp[(size_t)(gr + r) * N + gc] = f2bf(acc[mi][ni][r]);
      }
    }
  } else {
#pragma unroll
    for (int mi = 0; mi < 8; ++mi) {
      const int gr = row0 + wm * 128 + mi * 16 + quad * 4;
#pragma unroll
      for (int ni = 0; ni < 4; ++ni) {
        const int gc = col0 + wn * 64 + ni * 16 + lane16;
        const float bs = bias[gc];
#pragma unroll
        for (int r = 0; r < 4; ++r) {
          float v = acc[mi][ni][r] + bs;
          if (RELU) v = fmaxf(v, 0.0f);
          Cb[(size_t)(gr + r) * N + gc] = f2bf(v);
        }
      }
    }
  }
}

// ---------------- MFMA flash attention v2 (no-max softmax) ----------------
__global__ __launch_bounds__(256) void attn_mfma(const ushort_t* __restrict__ QKVb,
                                                 const ushort_t* __restrict__ Vtb,
                                                 ushort_t* __restrict__ Ob) {
  const int nh = blockIdx.x, qt = blockIdx.y;
  const int n = nh >> 4, h = nh & 15;
  const int tid = threadIdx.x;
  const int w = tid >> 6, l = tid & 63;
  const int lane16 = l & 15, quad = l >> 4;

  __shared__ __align__(16) ushort_t Ks[2][4096];
  __shared__ __align__(16) ushort_t Vs[2][4096];
  __shared__ __align__(16) ushort_t Ps[2][128][PD];

  const int q0 = qt * 128;

  short8 aq[2][2];
#pragma unroll
  for (int qf = 0; qf < 2; ++qf)
#pragma unroll
    for (int ks = 0; ks < 2; ++ks)
      aq[qf][ks] = *(const short8*)(QKVb +
          (size_t)(n * SEQ + q0 + w * 32 + qf * 16 + lane16) * 3072 +
          h * 64 + ks * 32 + quad * 8);

  const int lr8 = l >> 3;
  const int swsl = ((l & 7) ^ lr8) << 3;
  const int ldst = (w * 16) * 64;
  const int rx = lane16 & 7;

  float l_i[2][4] = {{0.f,0.f,0.f,0.f},{0.f,0.f,0.f,0.f}};
  f32x4 o_acc[2][4] = {};

#define STAGE_K(bf, kt, i) gld_lds16(&Ks[bf][ldst + (i) * 512], \
    QKVb + (size_t)(n * SEQ + (kt) * 64 + w * 16 + (i) * 8 + lr8) * 3072 + \
    1024 + h * 64 + swsl)
#define STAGE_V(bf, kt, i) gld_lds16(&Vs[bf][ldst + (i) * 512], \
    Vtb + (size_t)(nh * 64 + w * 16 + (i) * 8 + lr8) * SEQ + (kt) * 64 + swsl)

  STAGE_K(0, 0, 0); STAGE_K(0, 0, 1);
  STAGE_V(0, 0, 0); STAGE_V(0, 0, 1);

  for (int kt = 0; kt < 16; ++kt) {
    const int b = kt & 1;
    const int nx = (kt < 15) ? kt + 1 : 15;
    STAGE_K(b ^ 1, nx, 0); STAGE_K(b ^ 1, nx, 1);
    STAGE_V(b ^ 1, nx, 0); STAGE_V(b ^ 1, nx, 1);
    asm volatile("s_waitcnt vmcnt(4)" ::: "memory");
    __builtin_amdgcn_s_barrier();

    f32x4 s[2][4] = {};
    __builtin_amdgcn_s_setprio(1);
#pragma unroll
    for (int ks = 0; ks < 2; ++ks)
#pragma unroll
      for (int ni = 0; ni < 4; ++ni) {
        const int row = ni * 16 + lane16;
        short8 bk = *(const short8*)&Ks[b][row * 64 + (((ks * 4 + quad) ^ rx) << 3)];
        s[0][ni] = __builtin_amdgcn_mfma_f32_16x16x32_bf16(aq[0][ks], bk, s[0][ni], 0, 0, 0);
        s[1][ni] = __builtin_amdgcn_mfma_f32_16x16x32_bf16(aq[1][ks], bk, s[1][ni], 0, 0, 0);
      }
    __builtin_amdgcn_s_setprio(0);

#pragma unroll
    for (int qf = 0; qf < 2; ++qf)
#pragma unroll
      for (int ni = 0; ni < 4; ++ni)
#pragma unroll
        for (int r = 0; r < 4; ++r) {
          float p = __expf(s[qf][ni][r] * 0.125f);
          l_i[qf][r] += p;
          Ps[ni >> 1][w * 32 + qf * 16 + quad * 4 + r][(ni & 1) * 16 + lane16] = f2bf(p);
        }

    __builtin_amdgcn_s_setprio(1);
#pragma unroll
    for (int ks = 0; ks < 2; ++ks) {
      short8 ap0 = *(const short8*)&Ps[ks][w * 32 + lane16][quad * 8];
      short8 ap1 = *(const short8*)&Ps[ks][w * 32 + 16 + lane16][quad * 8];
#pragma unroll
      for (int nd = 0; nd < 4; ++nd) {
        const int row = nd * 16 + lane16;
        short8 bv = *(const short8*)&Vs[b][row * 64 + (((ks * 4 + quad) ^ rx) << 3)];
        o_acc[0][nd] = __builtin_amdgcn_mfma_f32_16x16x32_bf16(ap0, bv, o_acc[0][nd], 0, 0, 0);
        o_acc[1][nd] = __builtin_amdgcn_mfma_f32_16x16x32_bf16(ap1, bv, o_acc[1][nd], 0, 0, 0);
      }
    }
    __builtin_amdgcn_s_setprio(0);
    __builtin_amdgcn_s_barrier();
  }

#undef STAGE_K
#undef STAGE_V

#pragma unroll
  for (int qf = 0; qf < 2; ++qf)
#pragma unroll
    for (int r = 0; r < 4; ++r) {
      float li = l_i[qf][r];
#pragma unroll
      for (int m = 1; m <= 8; m <<= 1)
        li += __shfl_xor(li, m, 64);
      const float inv = 1.0f / li;
      const int gq = n * SEQ + q0 + w * 32 + qf * 16 + quad * 4 + r;
#pragma unroll
      for (int nd = 0; nd < 4; ++nd)
        Ob[(size_t)gq * HDIM + h * 64 + nd * 16 + lane16] = f2bf(o_acc[qf][nd][r] * inv);
    }
}

// -------- LayerNorm(p0+p1+bias) * g + b + resid; optional bf16 copy -------
template<bool WB>
__global__ __launch_bounds__(256) void ln_sum2_kernel(const float* __restrict__ p0,
                                                      const float* __restrict__ p1,
                                                      const float* __restrict__ bias,
                                                      const float* __restrict__ resid,
                                                      const float* __restrict__ g,
                                                      const float* __restrict__ b,
                                                      float* __restrict__ out,
                                                      ushort_t* __restrict__ outb) {
  const int row = blockIdx.x;
  const int tid = threadIdx.x;
  const size_t base = (size_t)row * HDIM;
  float v[4];
  float s = 0.0f, sq = 0.0f;
#pragma unroll
  for (int i = 0; i < 4; ++i) {
    int c = tid + i * 256;
    v[i] = p0[base + c] + p1[base + c] + bias[c];
    s += v[i];
    sq += v[i] * v[i];
  }
  for (int off = 32; off; off >>= 1) {
    s += __shfl_down(s, off, 64);
    sq += __shfl_down(sq, off, 64);
  }
  __shared__ float redA[4], redB[4], bc[2];
  const int wave = tid >> 6;
  if ((tid & 63) == 0) { redA[wave] = s; redB[wave] = sq; }
  __syncthreads();
  if (tid == 0) {
    float S = redA[0] + redA[1] + redA[2] + redA[3];
    float Q = redB[0] + redB[1] + redB[2] + redB[3];
    float mean = S * (1.0f / HDIM);
    bc[0] = mean;
    bc[1] = rsqrtf(Q * (1.0f / HDIM) - mean * mean + 1e-5f);
  }
  __syncthreads();
  const float mean = bc[0], rstd = bc[1];
#pragma unroll
  for (int i = 0; i < 4; ++i) {
    int c = tid + i * 256;
    float y = (v[i] - mean) * rstd * g[c] + b[c] + resid[base + c];
    out[base + c] = y;
    if constexpr (WB) outb[base + c] = f2bf(y);
  }
}

// -------- LayerNorm(sum of 4 BF16 partials + bias) * g + b + resid --------
__global__ __launch_bounds__(256) void ln_sum4b_kernel(const ushort_t* __restrict__ pb,
                                                       const float* __restrict__ bias,
                                                       const float* __restrict__ resid,
                                                       const float* __restrict__ g,
                                                       const float* __restrict__ b,
                                                       float* __restrict__ out) {
  const int row = blockIdx.x;
  const int tid = threadIdx.x;
  const size_t base = (size_t)row * HDIM;
  const int c0 = tid * 4;
  const size_t MN = (size_t)ROWS * HDIM;

  float4 bi = *(const float4*)&bias[c0];
  float v[4] = {bi.x, bi.y, bi.z, bi.w};
#pragma unroll
  for (int zz = 0; zz < 4; ++zz) {
    ushort4 u = *(const ushort4*)&pb[zz * MN + base + c0];
    v[0] += bf2f(u.x); v[1] += bf2f(u.y); v[2] += bf2f(u.z); v[3] += bf2f(u.w);
  }
  float s = v[0] + v[1] + v[2] + v[3];
  float sq = v[0]*v[0] + v[1]*v[1] + v[2]*v[2] + v[3]*v[3];
  for (int off = 32; off; off >>= 1) {
    s += __shfl_down(s, off, 64);
    sq += __shfl_down(sq, off, 64);
  }
  __shared__ float redA[4], redB[4], bc2[2];
  const int wave = tid >> 6;
  if ((tid & 63) == 0) { redA[wave] = s; redB[wave] = sq; }
  __syncthreads();
  if (tid == 0) {
    float S = redA[0] + redA[1] + redA[2] + redA[3];
    float Q = redB[0] + redB[1] + redB[2] + redB[3];
    float mean = S * (1.0f / HDIM);
    bc2[0] = mean;
    bc2[1] = rsqrtf(Q * (1.0f / HDIM) - mean * mean + 1e-5f);
  }
  __syncthreads();
  const float mean = bc2[0], rstd = bc2[1];
  float4 gg = *(const float4*)&g[c0];
  float4 bb = *(const float4*)&b[c0];
  float4 rr = *(const float4*)&resid[base + c0];
  float4 o;
  o.x = (v[0] - mean) * rstd * gg.x + bb.x + rr.x;
  o.y = (v[1] - mean) * rstd * gg.y + bb.y + rr.y;
  o.z = (v[2] - mean) * rstd * gg.z + bb.z + rr.z;
  o.w = (v[3] - mean) * rstd * gg.w + bb.w + rr.w;
  *(float4*)&out[base + c0] = o;
}

extern "C" void kernel_launch(void* const* d_in, const int* in_sizes, int n_in,
                              void* d_out, int out_size, void* d_ws, size_t ws_size,
                              hipStream_t stream) {
  const float* x    = (const float*)d_in[0];
  const float* Wq   = (const float*)d_in[2];
  const float* bq   = (const float*)d_in[3];
  const float* Wk   = (const float*)d_in[4];
  const float* bk   = (const float*)d_in[5];
  const float* Wv   = (const float*)d_in[6];
  const float* bv   = (const float*)d_in[7];
  const float* Wo   = (const float*)d_in[8];
  const float* bo   = (const float*)d_in[9];
  const float* g1   = (const float*)d_in[10];
  const float* b1n  = (const float*)d_in[11];
  const float* W1   = (const float*)d_in[12];
  const float* b1   = (const float*)d_in[13];
  const float* W2   = (const float*)d_in[14];
  const float* b2   = (const float*)d_in[15];
  const float* g2   = (const float*)d_in[16];
  const float* b2n  = (const float*)d_in[17];

  char* ws = (char*)d_ws;
  const size_t MB = 1024 * 1024;
  ushort_t* qkvb   = (ushort_t*)(ws + 0);         // 24 MB (dead after attn)
  float*    p0     = (float*)(ws + 0);            // Wo partial z=0 (fp32 16MB)
  float*    p1     = (float*)(ws + 16 * MB);      // Wo partial z=1
  ushort_t* pb     = (ushort_t*)(ws + 0);         // FFN2 bf16 partials 4x8MB
  ushort_t* vtb    = (ushort_t*)(ws + 24 * MB);   // 8 MB (attention-time)
  float*    x1     = (float*)(ws + 32 * MB);      // 16 MB
  ushort_t* x1b    = (ushort_t*)(ws + 48 * MB);   // 8 MB
  ushort_t* ctxb   = (ushort_t*)(ws + 56 * MB);   // 8 MB
  ushort_t* hb     = (ushort_t*)(ws + 64 * MB);   // 32 MB
  ushort_t* xb     = (ushort_t*)(ws + 64 * MB);   // reuse hb region pre-FFN1
  ushort_t* Wqkvt  = (ushort_t*)(ws + 96 * MB);   // 6 MB
  ushort_t* Wot    = (ushort_t*)(ws + 102 * MB);  // 2 MB
  ushort_t* W1t    = (ushort_t*)(ws + 104 * MB);  // 8 MB
  ushort_t* W2t    = (ushort_t*)(ws + 112 * MB);  // 8 MB
  float*    bqkv   = (float*)(ws + 120 * MB);     // 12 KB

  dim3 blk(256);

  // weights transpose + x->bf16 + bias concat, one dispatch
  prep_all<<<dim3(128, 32, 8), blk, 0, stream>>>(Wq, Wk, Wv, Wo, W1, W2,
                                                 Wqkvt, Wot, W1t, W2t,
                                                 x, xb, bq, bk, bv, bqkv);

  // fused QKV GEMM -> bf16 (256^2 2-bar/tile; grid 12x16 = 192 blocks)
  gemm256<false, false, 1><<<dim3(3072 / 256, ROWS / 256), dim3(512), 0, stream>>>(
      xb, Wqkvt, bqkv, qkvb, ROWS, 3072, HDIM);

  vtrans_k<<<dim3(SEQ / 32, 2, NBATCH * NHEAD), blk, 0, stream>>>(qkvb, vtb);

  // attention v2: grid (64, 8), QBLK=128
  attn_mfma<<<dim3(NBATCH * NHEAD, SEQ / 128), blk, 0, stream>>>(qkvb, vtb, ctxb);

  // ctx @ Wo, split-K=2 -> p0,p1 fp32; bias folded into LN1
  gemm_mfma<false, true, false, 2><<<dim3(HDIM / 128, ROWS / 128, 2), blk, 0, stream>>>(
      ctxb, Wot, nullptr, p0, nullptr, ROWS, HDIM, HDIM);

  ln_sum2_kernel<true><<<dim3(ROWS), blk, 0, stream>>>(p0, p1, bo, x, g1, b1n, x1, x1b);

  // FFN1 + ReLU -> hb bf16 (256^2 2-bar/tile; grid 16x16 = 256 blocks)
  gemm256<true, false, 1><<<dim3(FDIM / 256, ROWS / 256), dim3(512), 0, stream>>>(
      x1b, W1t, b1, hb, ROWS, FDIM, HDIM);

  // FFN2: 256^2 2-bar/tile split-K=4 (grid 4x16x4 = 256 blocks, Kh=1024);
  // bf16 partials to pb[0..4) (4x8MB at ws[0,32M)); bias folded into LN2.
  gemm256<false, true, 4><<<dim3(HDIM / 256, ROWS / 256, 4), dim3(512), 0, stream>>>(
      hb, W2t, nullptr, pb, ROWS, HDIM, FDIM);

  ln_sum4b_kernel<<<dim3(ROWS), blk, 0, stream>>>(pb, b2, x1, g2, b2n, (float*)d_out);
}

// Round 8
// 317.783 us; speedup vs baseline: 1.0142x; 1.0142x over previous
//
#include <hip/hip_runtime.h>
#include <hip/hip_bf16.h>

// EncoderLayer: N=4, L=1024, H=1024, HEADS=16, HS=64, FFN=4096
// fp32 in/out. GEMMs + attention via bf16 MFMA (16x16x32), fp32 accumulate.
// QKV, FFN1, FFN2 use the 256^2 2-bar-per-K-tile counted-vmcnt GEMM.
//   Round 8: broke the intra-wave WAR serialization (R1->M1->R2->M2) by
//   adding a third A-fragment register set. 20 of 24 ds_reads issue up
//   front; cluster1 (aA*b0) frees aA; the last 4 reads (mb4,k1 -> aA)
//   land under clusters 2-3 (aB*b1, aC*b0); cluster4 (aA*b1) is pure-reg
//   after the barrier. LDS port (~2300 cyc/tile/CU) and matrix pipe
//   (~2480 cyc) now overlap instead of summing (round-7 PM arithmetic).
//   128 arch VGPR + 128 acc = 256/wave = exactly the 2-waves/SIMD budget.
//   FFN2 runs split-K=4 (grid 4x16x4, Kh=1024) writing BF16 partials.
// Wo remains 128^2 split-K=2 with fp32 partials.
// Attention v2: QBLK=128, K/V via global_load_lds into XOR-swizzled LDS,
//   double-buffered counted vmcnt(4); Q in registers; setprio on MFMA.
// prep_all: one dispatch = 6 weight transposes + x->bf16 + bias concat.
//
// Workspace (<= ~121 MB):
//   [0,32M)    Wo partials p0,p1 (fp32 16MB ea) -> later FFN2 bf16 partials
//              pb[4] (8MB ea, contiguous); qkvb bf16 [0,24M) pre-attn;
//              vtb bf16 [24,32M) attention-time.
//   [32,48M)   x1 fp32
//   [48,56M)   x1b bf16
//   [56,64M)   ctxb bf16
//   [64,96M)   hb bf16 [4096][4096]; xb bf16 lives here pre-FFN1
//   [96,102M)  Wqkvt bf16, [102,104M) Wot, [104,112M) W1t, [112,120M) W2t
//   [120M,..)  bias_qkv fp32 [3072]

#define HDIM 1024
#define FDIM 4096
#define ROWS 4096
#define NHEAD 16
#define HS 64
#define SEQ 1024
#define NBATCH 4
#define PD 40

typedef unsigned short ushort_t;
typedef short short8 __attribute__((ext_vector_type(8)));
typedef float f32x4 __attribute__((ext_vector_type(4)));

__device__ __forceinline__ ushort_t f2bf(float v) {
  union { float f; unsigned int u; } c; c.f = v;
  unsigned int u = c.u;
  u += 0x7fffu + ((u >> 16) & 1u);
  return (ushort_t)(u >> 16);
}

__device__ __forceinline__ float bf2f(ushort_t u) {
  union { unsigned int u; float f; } c;
  c.u = ((unsigned int)u) << 16;
  return c.f;
}

__device__ __forceinline__ void gld_lds16(ushort_t* lds, const ushort_t* g) {
  __builtin_amdgcn_global_load_lds(
      (const __attribute__((address_space(1))) unsigned int*)g,
      (__attribute__((address_space(3))) unsigned int*)lds, 16, 0, 0);
}

// ---------------- prep: 6 weight transposes + x->bf16 + bias concat -------
// grid (128, 32, 8). z 0..3: Wq,Wk,Wv,Wo (bx<32); z=4: W1; z=5: W2;
// z=6: x fp32 -> xb bf16; z=7: concat biases.
__global__ __launch_bounds__(256) void prep_all(const float* __restrict__ s0,
                                                const float* __restrict__ s1,
                                                const float* __restrict__ s2,
                                                const float* __restrict__ s3,
                                                const float* __restrict__ s4,
                                                const float* __restrict__ s5,
                                                ushort_t* __restrict__ dqkv,
                                                ushort_t* __restrict__ dot,
                                                ushort_t* __restrict__ d1,
                                                ushort_t* __restrict__ d2,
                                                const float* __restrict__ x,
                                                ushort_t* __restrict__ xb,
                                                const float* __restrict__ ba,
                                                const float* __restrict__ bb,
                                                const float* __restrict__ bc,
                                                float* __restrict__ bqkv) {
  const int z = blockIdx.z;
  if (z == 6) {
    int i = (blockIdx.y * 128 + blockIdx.x) * 256 + threadIdx.x;  // < 1M float4s
    float4 v = ((const float4*)x)[i];
    ushort4 o;
    o.x = f2bf(v.x); o.y = f2bf(v.y); o.z = f2bf(v.z); o.w = f2bf(v.w);
    ((ushort4*)xb)[i] = o;
    return;
  }
  if (z == 7) {
    if (blockIdx.y != 0 || blockIdx.x >= 12) return;
    int i = blockIdx.x * 256 + threadIdx.x;
    float v = (i < 1024) ? ba[i] : (i < 2048 ? bb[i - 1024] : bc[i - 2048]);
    bqkv[i] = v;
    return;
  }
  __shared__ float t[32][33];
  const float* src;
  ushort_t* dst;
  int K, N, n0, k0;
  if (z < 4) {
    if (blockIdx.x >= 32) return;
    src = (z == 0) ? s0 : (z == 1) ? s1 : (z == 2) ? s2 : s3;
    dst = (z < 3) ? (dqkv + (size_t)z * 1024 * 1024) : dot;
    K = 1024; N = 1024; n0 = blockIdx.x * 32; k0 = blockIdx.y * 32;
  } else if (z == 4) {
    src = s4; dst = d1; K = 1024; N = 4096;
    n0 = blockIdx.x * 32; k0 = blockIdx.y * 32;
  } else {
    src = s5; dst = d2; K = 4096; N = 1024;
    n0 = blockIdx.y * 32; k0 = blockIdx.x * 32;
  }
  int c = threadIdx.x & 31, r0 = (threadIdx.x >> 5) * 4;
#pragma unroll
  for (int i = 0; i < 4; ++i)
    t[r0 + i][c] = src[(size_t)(k0 + r0 + i) * N + n0 + c];
  __syncthreads();
#pragma unroll
  for (int i = 0; i < 4; ++i)
    dst[(size_t)(n0 + r0 + i) * K + k0 + c] = f2bf(t[c][r0 + i]);
}

__global__ __launch_bounds__(256) void vtrans_k(const ushort_t* __restrict__ qkvb,
                                                ushort_t* __restrict__ vtb) {
  __shared__ ushort_t t[32][33];
  int t0 = blockIdx.x * 32, d0 = blockIdx.y * 32, nh = blockIdx.z;
  int n = nh >> 4, h = nh & 15;
  int c = threadIdx.x & 31, r0 = (threadIdx.x >> 5) * 4;
#pragma unroll
  for (int i = 0; i < 4; ++i)
    t[r0 + i][c] = qkvb[(size_t)(n * SEQ + t0 + r0 + i) * 3072 + 2048 + h * 64 + d0 + c];
  __syncthreads();
#pragma unroll
  for (int i = 0; i < 4; ++i)
    vtb[(size_t)(nh * 64 + d0 + r0 + i) * SEQ + t0 + c] = t[c][r0 + i];
}

// ---------------- 128^2 MFMA GEMM (kept for Wo split-K=2) -----------------
template<bool RELU, bool OUT_F32, bool OUT_BF16, int SPLITK>
__global__ __launch_bounds__(256) void gemm_mfma(const ushort_t* __restrict__ A,
                                                 const ushort_t* __restrict__ Bt,
                                                 const float* __restrict__ bias,
                                                 float* __restrict__ Cf,
                                                 ushort_t* __restrict__ Cb,
                                                 int M, int N, int K) {
  __shared__ __align__(16) ushort_t As[128 * 32];
  __shared__ __align__(16) ushort_t Bs[128 * 32];
  const int tid = threadIdx.x;
  const int w = tid >> 6, l = tid & 63;
  const int lane16 = l & 15, quad = l >> 4;
  const int wm = w & 1, wn = w >> 1;

  const int flat = blockIdx.y * gridDim.x + blockIdx.x;
  const int per = (gridDim.x * gridDim.y) >> 3;
  const int nf = (flat & 7) * per + (flat >> 3);
  const int bx = nf % gridDim.x;
  const int by = nf / gridDim.x;

  const int row0 = by * 128, col0 = bx * 128;
  const int z = (SPLITK > 1) ? blockIdx.z : 0;
  const int Kh = K / SPLITK;
  const int kbeg = z * Kh;

  const ushort_t* Ag = A + (size_t)row0 * K;
  const ushort_t* Bg = Bt + (size_t)col0 * K;

  f32x4 acc[4][4] = {};
  const int fr = tid >> 2;
  const int fc = (tid & 3) << 3;

  for (int kt = kbeg; kt < kbeg + Kh; kt += 32) {
#pragma unroll
    for (int rnd = 0; rnd < 2; ++rnd) {
      int r = fr + rnd * 64;
      ushort_t* ldsA = &As[(size_t)(rnd * 256 + w * 64) * 8];
      ushort_t* ldsB = &Bs[(size_t)(rnd * 256 + w * 64) * 8];
      gld_lds16(ldsA, Ag + (size_t)r * K + kt + fc);
      gld_lds16(ldsB, Bg + (size_t)r * K + kt + fc);
    }
    __syncthreads();
    short8 af[4], bfr[4];
#pragma unroll
    for (int i = 0; i < 4; ++i) {
      af[i]  = *(const short8*)&As[(wm * 64 + i * 16 + lane16) * 32 + quad * 8];
      bfr[i] = *(const short8*)&Bs[(wn * 64 + i * 16 + lane16) * 32 + quad * 8];
    }
#pragma unroll
    for (int mi = 0; mi < 4; ++mi)
#pragma unroll
      for (int ni = 0; ni < 4; ++ni)
        acc[mi][ni] = __builtin_amdgcn_mfma_f32_16x16x32_bf16(
            af[mi], bfr[ni], acc[mi][ni], 0, 0, 0);
    __syncthreads();
  }

  float* Cp = (SPLITK > 1) ? (Cf + (size_t)z * M * N) : Cf;
#pragma unroll
  for (int mi = 0; mi < 4; ++mi) {
    int gr = row0 + wm * 64 + mi * 16 + quad * 4;
#pragma unroll
    for (int ni = 0; ni < 4; ++ni) {
      int gc = col0 + wn * 64 + ni * 16 + lane16;
      float bs = (SPLITK > 1) ? 0.0f : bias[gc];
#pragma unroll
      for (int r = 0; r < 4; ++r) {
        float v = acc[mi][ni][r] + bs;
        if (RELU) v = fmaxf(v, 0.0f);
        size_t idx = (size_t)(gr + r) * N + gc;
        if constexpr (OUT_F32) Cp[idx] = v;
        if constexpr (OUT_BF16) Cb[idx] = f2bf(v);
      }
    }
  }
}

// ---------------- 256^2 2-barrier-per-tile counted-vmcnt GEMM -------------
// C = A(MxK,bf16) @ Bt(NxK,bf16)^T [+ bias] [, ReLU].
// PBF16: bf16 partials (no bias) to Cb + z*M*N; else bf16+bias to Cb.
// 8 waves (2Mx4N), XOR-swizzled LDS, pre-swizzled global_load_lds source.
// One phase per K-tile t (buf b = t&1, prefetch s = min(t+2, last)):
//   R1: 20 ds_reads (aA=mb0k0, aB=mb0k1, b0=k0, b1=k1, aC=mb4k0)
//   M1: 16 MFMA acc[0..3] += aA*b0       (frees aA)
//   R2: 4 ds_reads aA <- mb4k1           (lands under M2/M3)
//   M2: 16 MFMA acc[0..3] += aB*b1
//   M3: 16 MFMA acc[4..7] += aC*b0
//   lgkmcnt(0); BAR#1   <- WAR fence: all 24 reads of buf[b] drained
//   STAGE tile s -> buf[b] (8 gld)
//   M4: 16 MFMA acc[4..7] += aA*b1       (pure register)
//   vmcnt(8)  <- drains tile t+1's 8 stages, leaves tile s's 8 in flight
//   BAR#2     <- publishes buf[b^1]
// 3 A-sets break the R/M WAR serialization (round-7 PM): LDS port and
// matrix pipe overlap. 128 arch VGPR + 128 acc = 2-waves/SIMD budget.
template<bool RELU, bool PBF16, int SPLITK>
__global__ __launch_bounds__(512, 2) void gemm256(const ushort_t* __restrict__ A,
                                                  const ushort_t* __restrict__ Bt,
                                                  const float* __restrict__ bias,
                                                  ushort_t* __restrict__ Cb,
                                                  int M, int N, int K) {
  __shared__ __align__(16) ushort_t sA[2][16384];
  __shared__ __align__(16) ushort_t sB[2][16384];
  const int tid = threadIdx.x;
  const int w = tid >> 6, l = tid & 63;
  const int lane16 = l & 15, quad = l >> 4;
  const int wm = w >> 2, wn = w & 3;

  const int gx = gridDim.x;
  const int flat = blockIdx.y * gx + blockIdx.x;
  const int per = (gx * gridDim.y) >> 3;
  const int nf = (flat & 7) * per + (flat >> 3);
  const int bx = nf % gx, by = nf / gx;
  const int row0 = by * 256, col0 = bx * 256;

  const int z = (SPLITK > 1) ? blockIdx.z : 0;
  const int Kh = K / SPLITK;
  const int kbeg = z * Kh;

  const ushort_t* Ag = A + (size_t)row0 * K + kbeg;
  const ushort_t* Bg = Bt + (size_t)col0 * K + kbeg;

  const int lr8 = l >> 3, lsl = l & 7;
  const size_t stg = (size_t)(w * 8 + lr8) * K + (size_t)((lsl ^ lr8) << 3);
  const int wslab = w * 512;

  const int rowA = (wm * 128 + lane16) * 64;
  const int rowB = (wn * 64 + lane16) * 64;
  const int sl0 = (quad ^ (lane16 & 7)) * 8;

  f32x4 acc[8][4] = {};
  short8 aA[4], aB[4], aC[4], b0[4], b1[4];

#define STAGE_A(bf, t, q) gld_lds16(&sA[bf][(q) * 4096 + wslab], \
    Ag + stg + (size_t)(q) * 64 * (size_t)K + (size_t)(t) * 64)
#define STAGE_B(bf, t, q) gld_lds16(&sB[bf][(q) * 4096 + wslab], \
    Bg + stg + (size_t)(q) * 64 * (size_t)K + (size_t)(t) * 64)
#define STAGE_ALL(bf, t) { \
    STAGE_A(bf, t, 0); STAGE_A(bf, t, 1); STAGE_A(bf, t, 2); STAGE_A(bf, t, 3); \
    STAGE_B(bf, t, 0); STAGE_B(bf, t, 1); STAGE_B(bf, t, 2); STAGE_B(bf, t, 3); }
#define LDAE(bf, mi, ks) (*(const short8*)&sA[bf][rowA + (mi) * 1024 + (sl0 ^ ((ks) * 32))])
#define LDBE(bf, ni, ks) (*(const short8*)&sB[bf][rowB + (ni) * 1024 + (sl0 ^ ((ks) * 32))])
#define LD_A4(dst, bf, mb, ks) { \
    dst[0] = LDAE(bf, (mb) + 0, ks); dst[1] = LDAE(bf, (mb) + 1, ks); \
    dst[2] = LDAE(bf, (mb) + 2, ks); dst[3] = LDAE(bf, (mb) + 3, ks); }
#define LD_B2(bf) { \
    b0[0] = LDBE(bf, 0, 0); b0[1] = LDBE(bf, 1, 0); \
    b0[2] = LDBE(bf, 2, 0); b0[3] = LDBE(bf, 3, 0); \
    b1[0] = LDBE(bf, 0, 1); b1[1] = LDBE(bf, 1, 1); \
    b1[2] = LDBE(bf, 2, 1); b1[3] = LDBE(bf, 3, 1); }
#define MFMA16(MB, AV, BV) { \
    _Pragma("unroll") for (int mi = 0; mi < 4; ++mi) { \
      _Pragma("unroll") for (int ni = 0; ni < 4; ++ni) \
        acc[(MB) + mi][ni] = __builtin_amdgcn_mfma_f32_16x16x32_bf16( \
            AV[mi], BV[ni], acc[(MB) + mi][ni], 0, 0, 0); \
    } }
#define BAR() __builtin_amdgcn_s_barrier()
#define WAIT_LGKM() asm volatile("s_waitcnt lgkmcnt(0)" ::: "memory")
#define WAIT_VM8() asm volatile("s_waitcnt vmcnt(8)" ::: "memory")

  // prologue: tile0 -> buf0, tile1 -> buf1 (8 loads each)
  STAGE_ALL(0, 0);
  STAGE_ALL(1, 1);
  WAIT_VM8();   // tile0's 8 landed; tile1's 8 in flight
  BAR();

  const int last = (Kh >> 6) - 1;
  const int nt = Kh >> 6;  // Kh multiple of 128 -> nt even, >= 2
  for (int t = 0; t < nt; ++t) {
    const int b = t & 1;
    int s = t + 2;
    if (s > last) s = last;

    // R1: 20 reads up front
    LD_A4(aA, b, 0, 0); LD_A4(aB, b, 0, 1); LD_B2(b); LD_A4(aC, b, 4, 0);
    // M1 (frees aA); R2 lands under M2/M3
    __builtin_amdgcn_s_setprio(1); MFMA16(0, aA, b0); __builtin_amdgcn_s_setprio(0);
    LD_A4(aA, b, 4, 1);
    __builtin_amdgcn_s_setprio(1);
    MFMA16(0, aB, b1);
    MFMA16(4, aC, b0);
    __builtin_amdgcn_s_setprio(0);
    WAIT_LGKM();               // WAR fence: this wave's buf[b] reads drained
    BAR();                     // all waves' reads of buf[b] complete
    STAGE_ALL(b, s);           // overwrite buf[b] with tile s
    __builtin_amdgcn_s_setprio(1); MFMA16(4, aA, b1); __builtin_amdgcn_s_setprio(0);
    WAIT_VM8();                // tile t+1 fully landed in buf[b^1]
    BAR();                     // publish
  }

#undef STAGE_A
#undef STAGE_B
#undef STAGE_ALL
#undef LDAE
#undef LDBE
#undef LD_A4
#undef LD_B2
#undef MFMA16
#undef BAR
#undef WAIT_LGKM
#undef WAIT_VM8

  if constexpr (PBF16) {
    ushort_t* Cp = Cb + (size_t)z * M * N;
#pragma unroll
    for (int mi = 0; mi < 8; ++mi) {
      const int gr = row0 + wm * 128 + mi * 16 + quad * 4;
#pragma unroll
      for (int ni = 0; ni < 4; ++ni) {
        const int gc = col0 + wn * 64 + ni * 16 + lane16;
#pragma unroll
        for (int r = 0; r < 4; ++r)
          Cp[(size_t)(gr + r) * N + gc] = f2bf(acc[mi][ni][r]);
      }
    }
  } else {
#pragma unroll
    for (int mi = 0; mi < 8; ++mi) {
      const int gr = row0 + wm * 128 + mi * 16 + quad * 4;
#pragma unroll
      for (int ni = 0; ni < 4; ++ni) {
        const int gc = col0 + wn * 64 + ni * 16 + lane16;
        const float bs = bias[gc];
#pragma unroll
        for (int r = 0; r < 4; ++r) {
          float v = acc[mi][ni][r] + bs;
          if (RELU) v = fmaxf(v, 0.0f);
          Cb[(size_t)(gr + r) * N + gc] = f2bf(v);
        }
      }
    }
  }
}

// ---------------- MFMA flash attention v2 (no-max softmax) ----------------
__global__ __launch_bounds__(256) void attn_mfma(const ushort_t* __restrict__ QKVb,
                                                 const ushort_t* __restrict__ Vtb,
                                                 ushort_t* __restrict__ Ob) {
  const int nh = blockIdx.x, qt = blockIdx.y;
  const int n = nh >> 4, h = nh & 15;
  const int tid = threadIdx.x;
  const int w = tid >> 6, l = tid & 63;
  const int lane16 = l & 15, quad = l >> 4;

  __shared__ __align__(16) ushort_t Ks[2][4096];
  __shared__ __align__(16) ushort_t Vs[2][4096];
  __shared__ __align__(16) ushort_t Ps[2][128][PD];

  const int q0 = qt * 128;

  short8 aq[2][2];
#pragma unroll
  for (int qf = 0; qf < 2; ++qf)
#pragma unroll
    for (int ks = 0; ks < 2; ++ks)
      aq[qf][ks] = *(const short8*)(QKVb +
          (size_t)(n * SEQ + q0 + w * 32 + qf * 16 + lane16) * 3072 +
          h * 64 + ks * 32 + quad * 8);

  const int lr8 = l >> 3;
  const int swsl = ((l & 7) ^ lr8) << 3;
  const int ldst = (w * 16) * 64;
  const int rx = lane16 & 7;

  float l_i[2][4] = {{0.f,0.f,0.f,0.f},{0.f,0.f,0.f,0.f}};
  f32x4 o_acc[2][4] = {};

#define STAGE_K(bf, kt, i) gld_lds16(&Ks[bf][ldst + (i) * 512], \
    QKVb + (size_t)(n * SEQ + (kt) * 64 + w * 16 + (i) * 8 + lr8) * 3072 + \
    1024 + h * 64 + swsl)
#define STAGE_V(bf, kt, i) gld_lds16(&Vs[bf][ldst + (i) * 512], \
    Vtb + (size_t)(nh * 64 + w * 16 + (i) * 8 + lr8) * SEQ + (kt) * 64 + swsl)

  STAGE_K(0, 0, 0); STAGE_K(0, 0, 1);
  STAGE_V(0, 0, 0); STAGE_V(0, 0, 1);

  for (int kt = 0; kt < 16; ++kt) {
    const int b = kt & 1;
    const int nx = (kt < 15) ? kt + 1 : 15;
    STAGE_K(b ^ 1, nx, 0); STAGE_K(b ^ 1, nx, 1);
    STAGE_V(b ^ 1, nx, 0); STAGE_V(b ^ 1, nx, 1);
    asm volatile("s_waitcnt vmcnt(4)" ::: "memory");
    __builtin_amdgcn_s_barrier();

    f32x4 s[2][4] = {};
    __builtin_amdgcn_s_setprio(1);
#pragma unroll
    for (int ks = 0; ks < 2; ++ks)
#pragma unroll
      for (int ni = 0; ni < 4; ++ni) {
        const int row = ni * 16 + lane16;
        short8 bk = *(const short8*)&Ks[b][row * 64 + (((ks * 4 + quad) ^ rx) << 3)];
        s[0][ni] = __builtin_amdgcn_mfma_f32_16x16x32_bf16(aq[0][ks], bk, s[0][ni], 0, 0, 0);
        s[1][ni] = __builtin_amdgcn_mfma_f32_16x16x32_bf16(aq[1][ks], bk, s[1][ni], 0, 0, 0);
      }
    __builtin_amdgcn_s_setprio(0);

#pragma unroll
    for (int qf = 0; qf < 2; ++qf)
#pragma unroll
      for (int ni = 0; ni < 4; ++ni)
#pragma unroll
        for (int r = 0; r < 4; ++r) {
          float p = __expf(s[qf][ni][r] * 0.125f);
          l_i[qf][r] += p;
          Ps[ni >> 1][w * 32 + qf * 16 + quad * 4 + r][(ni & 1) * 16 + lane16] = f2bf(p);
        }

    __builtin_amdgcn_s_setprio(1);
#pragma unroll
    for (int ks = 0; ks < 2; ++ks) {
      short8 ap0 = *(const short8*)&Ps[ks][w * 32 + lane16][quad * 8];
      short8 ap1 = *(const short8*)&Ps[ks][w * 32 + 16 + lane16][quad * 8];
#pragma unroll
      for (int nd = 0; nd < 4; ++nd) {
        const int row = nd * 16 + lane16;
        short8 bv = *(const short8*)&Vs[b][row * 64 + (((ks * 4 + quad) ^ rx) << 3)];
        o_acc[0][nd] = __builtin_amdgcn_mfma_f32_16x16x32_bf16(ap0, bv, o_acc[0][nd], 0, 0, 0);
        o_acc[1][nd] = __builtin_amdgcn_mfma_f32_16x16x32_bf16(ap1, bv, o_acc[1][nd], 0, 0, 0);
      }
    }
    __builtin_amdgcn_s_setprio(0);
    __builtin_amdgcn_s_barrier();
  }

#undef STAGE_K
#undef STAGE_V

#pragma unroll
  for (int qf = 0; qf < 2; ++qf)
#pragma unroll
    for (int r = 0; r < 4; ++r) {
      float li = l_i[qf][r];
#pragma unroll
      for (int m = 1; m <= 8; m <<= 1)
        li += __shfl_xor(li, m, 64);
      const float inv = 1.0f / li;
      const int gq = n * SEQ + q0 + w * 32 + qf * 16 + quad * 4 + r;
#pragma unroll
      for (int nd = 0; nd < 4; ++nd)
        Ob[(size_t)gq * HDIM + h * 64 + nd * 16 + lane16] = f2bf(o_acc[qf][nd][r] * inv);
    }
}

// -------- LayerNorm(p0+p1+bias) * g + b + resid; optional bf16 copy -------
template<bool WB>
__global__ __launch_bounds__(256) void ln_sum2_kernel(const float* __restrict__ p0,
                                                      const float* __restrict__ p1,
                                                      const float* __restrict__ bias,
                                                      const float* __restrict__ resid,
                                                      const float* __restrict__ g,
                                                      const float* __restrict__ b,
                                                      float* __restrict__ out,
                                                      ushort_t* __restrict__ outb) {
  const int row = blockIdx.x;
  const int tid = threadIdx.x;
  const size_t base = (size_t)row * HDIM;
  float v[4];
  float s = 0.0f, sq = 0.0f;
#pragma unroll
  for (int i = 0; i < 4; ++i) {
    int c = tid + i * 256;
    v[i] = p0[base + c] + p1[base + c] + bias[c];
    s += v[i];
    sq += v[i] * v[i];
  }
  for (int off = 32; off; off >>= 1) {
    s += __shfl_down(s, off, 64);
    sq += __shfl_down(sq, off, 64);
  }
  __shared__ float redA[4], redB[4], bc[2];
  const int wave = tid >> 6;
  if ((tid & 63) == 0) { redA[wave] = s; redB[wave] = sq; }
  __syncthreads();
  if (tid == 0) {
    float S = redA[0] + redA[1] + redA[2] + redA[3];
    float Q = redB[0] + redB[1] + redB[2] + redB[3];
    float mean = S * (1.0f / HDIM);
    bc[0] = mean;
    bc[1] = rsqrtf(Q * (1.0f / HDIM) - mean * mean + 1e-5f);
  }
  __syncthreads();
  const float mean = bc[0], rstd = bc[1];
#pragma unroll
  for (int i = 0; i < 4; ++i) {
    int c = tid + i * 256;
    float y = (v[i] - mean) * rstd * g[c] + b[c] + resid[base + c];
    out[base + c] = y;
    if constexpr (WB) outb[base + c] = f2bf(y);
  }
}

// -------- LayerNorm(sum of 4 BF16 partials + bias) * g + b + resid --------
__global__ __launch_bounds__(256) void ln_sum4b_kernel(const ushort_t* __restrict__ pb,
                                                       const float* __restrict__ bias,
                                                       const float* __restrict__ resid,
                                                       const float* __restrict__ g,
                                                       const float* __restrict__ b,
                                                       float* __restrict__ out) {
  const int row = blockIdx.x;
  const int tid = threadIdx.x;
  const size_t base = (size_t)row * HDIM;
  const int c0 = tid * 4;
  const size_t MN = (size_t)ROWS * HDIM;

  float4 bi = *(const float4*)&bias[c0];
  float v[4] = {bi.x, bi.y, bi.z, bi.w};
#pragma unroll
  for (int zz = 0; zz < 4; ++zz) {
    ushort4 u = *(const ushort4*)&pb[zz * MN + base + c0];
    v[0] += bf2f(u.x); v[1] += bf2f(u.y); v[2] += bf2f(u.z); v[3] += bf2f(u.w);
  }
  float s = v[0] + v[1] + v[2] + v[3];
  float sq = v[0]*v[0] + v[1]*v[1] + v[2]*v[2] + v[3]*v[3];
  for (int off = 32; off; off >>= 1) {
    s += __shfl_down(s, off, 64);
    sq += __shfl_down(sq, off, 64);
  }
  __shared__ float redA[4], redB[4], bc2[2];
  const int wave = tid >> 6;
  if ((tid & 63) == 0) { redA[wave] = s; redB[wave] = sq; }
  __syncthreads();
  if (tid == 0) {
    float S = redA[0] + redA[1] + redA[2] + redA[3];
    float Q = redB[0] + redB[1] + redB[2] + redB[3];
    float mean = S * (1.0f / HDIM);
    bc2[0] = mean;
    bc2[1] = rsqrtf(Q * (1.0f / HDIM) - mean * mean + 1e-5f);
  }
  __syncthreads();
  const float mean = bc2[0], rstd = bc2[1];
  float4 gg = *(const float4*)&g[c0];
  float4 bb = *(const float4*)&b[c0];
  float4 rr = *(const float4*)&resid[base + c0];
  float4 o;
  o.x = (v[0] - mean) * rstd * gg.x + bb.x + rr.x;
  o.y = (v[1] - mean) * rstd * gg.y + bb.y + rr.y;
  o.z = (v[2] - mean) * rstd * gg.z + bb.z + rr.z;
  o.w = (v[3] - mean) * rstd * gg.w + bb.w + rr.w;
  *(float4*)&out[base + c0] = o;
}

extern "C" void kernel_launch(void* const* d_in, const int* in_sizes, int n_in,
                              void* d_out, int out_size, void* d_ws, size_t ws_size,
                              hipStream_t stream) {
  const float* x    = (const float*)d_in[0];
  const float* Wq   = (const float*)d_in[2];
  const float* bq   = (const float*)d_in[3];
  const float* Wk   = (const float*)d_in[4];
  const float* bk   = (const float*)d_in[5];
  const float* Wv   = (const float*)d_in[6];
  const float* bv   = (const float*)d_in[7];
  const float* Wo   = (const float*)d_in[8];
  const float* bo   = (const float*)d_in[9];
  const float* g1   = (const float*)d_in[10];
  const float* b1n  = (const float*)d_in[11];
  const float* W1   = (const float*)d_in[12];
  const float* b1   = (const float*)d_in[13];
  const float* W2   = (const float*)d_in[14];
  const float* b2   = (const float*)d_in[15];
  const float* g2   = (const float*)d_in[16];
  const float* b2n  = (const float*)d_in[17];

  char* ws = (char*)d_ws;
  const size_t MB = 1024 * 1024;
  ushort_t* qkvb   = (ushort_t*)(ws + 0);         // 24 MB (dead after attn)
  float*    p0     = (float*)(ws + 0);            // Wo partial z=0 (fp32 16MB)
  float*    p1     = (float*)(ws + 16 * MB);      // Wo partial z=1
  ushort_t* pb     = (ushort_t*)(ws + 0);         // FFN2 bf16 partials 4x8MB
  ushort_t* vtb    = (ushort_t*)(ws + 24 * MB);   // 8 MB (attention-time)
  float*    x1     = (float*)(ws + 32 * MB);      // 16 MB
  ushort_t* x1b    = (ushort_t*)(ws + 48 * MB);   // 8 MB
  ushort_t* ctxb   = (ushort_t*)(ws + 56 * MB);   // 8 MB
  ushort_t* hb     = (ushort_t*)(ws + 64 * MB);   // 32 MB
  ushort_t* xb     = (ushort_t*)(ws + 64 * MB);   // reuse hb region pre-FFN1
  ushort_t* Wqkvt  = (ushort_t*)(ws + 96 * MB);   // 6 MB
  ushort_t* Wot    = (ushort_t*)(ws + 102 * MB);  // 2 MB
  ushort_t* W1t    = (ushort_t*)(ws + 104 * MB);  // 8 MB
  ushort_t* W2t    = (ushort_t*)(ws + 112 * MB);  // 8 MB
  float*    bqkv   = (float*)(ws + 120 * MB);     // 12 KB

  dim3 blk(256);

  // weights transpose + x->bf16 + bias concat, one dispatch
  prep_all<<<dim3(128, 32, 8), blk, 0, stream>>>(Wq, Wk, Wv, Wo, W1, W2,
                                                 Wqkvt, Wot, W1t, W2t,
                                                 x, xb, bq, bk, bv, bqkv);

  // fused QKV GEMM -> bf16 (256^2 2-bar/tile; grid 12x16 = 192 blocks)
  gemm256<false, false, 1><<<dim3(3072 / 256, ROWS / 256), dim3(512), 0, stream>>>(
      xb, Wqkvt, bqkv, qkvb, ROWS, 3072, HDIM);

  vtrans_k<<<dim3(SEQ / 32, 2, NBATCH * NHEAD), blk, 0, stream>>>(qkvb, vtb);

  // attention v2: grid (64, 8), QBLK=128
  attn_mfma<<<dim3(NBATCH * NHEAD, SEQ / 128), blk, 0, stream>>>(qkvb, vtb, ctxb);

  // ctx @ Wo, split-K=2 -> p0,p1 fp32; bias folded into LN1
  gemm_mfma<false, true, false, 2><<<dim3(HDIM / 128, ROWS / 128, 2), blk, 0, stream>>>(
      ctxb, Wot, nullptr, p0, nullptr, ROWS, HDIM, HDIM);

  ln_sum2_kernel<true><<<dim3(ROWS), blk, 0, stream>>>(p0, p1, bo, x, g1, b1n, x1, x1b);

  // FFN1 + ReLU -> hb bf16 (256^2 2-bar/tile; grid 16x16 = 256 blocks)
  gemm256<true, false, 1><<<dim3(FDIM / 256, ROWS / 256), dim3(512), 0, stream>>>(
      x1b, W1t, b1, hb, ROWS, FDIM, HDIM);

  // FFN2: 256^2 2-bar/tile split-K=4 (grid 4x16x4 = 256 blocks, Kh=1024);
  // bf16 partials to pb[0..4) (4x8MB at ws[0,32M)); bias folded into LN2.
  gemm256<false, true, 4><<<dim3(HDIM / 256, ROWS / 256, 4), dim3(512), 0, stream>>>(
      hb, W2t, nullptr, pb, ROWS, HDIM, FDIM);

  ln_sum4b_kernel<<<dim3(ROWS), blk, 0, stream>>>(pb, b2, x1, g2, b2n, (float*)d_out);
}

// Round 9
// 313.260 us; speedup vs baseline: 1.0288x; 1.0144x over previous
//
#include <hip/hip_runtime.h>
#include <hip/hip_bf16.h>

// EncoderLayer: N=4, L=1024, H=1024, HEADS=16, HS=64, FFN=4096
// fp32 in/out. GEMMs + attention via bf16 MFMA (16x16x32), fp32 accumulate.
// QKV, FFN1, FFN2: 256^2 2-bar-per-K-tile counted-vmcnt GEMM (at the
//   documented ~848 TF plateau for K=1024 256^2 on gfx950 — m248).
//   QKV epilogue writes V columns (col>=2048) TRANSPOSED straight to vtb
//   (ushort4 per thread: r=0..3 are consecutive t) — vtrans_k dispatch
//   eliminated, dead qkvb V-region write skipped.
//   FFN2 split-K=4 writes bf16 partials (round 4).
// Wo: 128^2 split-K=2, now with BF16 partials (same proven trick); LN1
//   reads the two bf16 partials vectorized.
// Attention v2: QBLK=128, K/V via global_load_lds into XOR-swizzled LDS,
//   double-buffered counted vmcnt(4); Q in registers; setprio on MFMA.
// prep_all: one dispatch = 6 weight transposes + x->bf16 + bias concat.
//
// Workspace (<= ~121 MB):
//   [0,16M)    Wo bf16 partials pw[2] (8MB ea)  (qkvb bf16 [0,24M) pre-attn;
//              FFN2 bf16 partials pb[4] (8MB ea) [0,32M) later)
//   [24,32M)   vtb bf16 (written by QKV epilogue; read by attn)
//   [32,48M)   x1 fp32
//   [48,56M)   x1b bf16
//   [56,64M)   ctxb bf16
//   [64,96M)   hb bf16; xb bf16 lives here pre-FFN1
//   [96,102M)  Wqkvt bf16, [102,104M) Wot, [104,112M) W1t, [112,120M) W2t
//   [120M,..)  bias_qkv fp32 [3072]

#define HDIM 1024
#define FDIM 4096
#define ROWS 4096
#define NHEAD 16
#define HS 64
#define SEQ 1024
#define NBATCH 4
#define PD 40

typedef unsigned short ushort_t;
typedef short short8 __attribute__((ext_vector_type(8)));
typedef float f32x4 __attribute__((ext_vector_type(4)));

__device__ __forceinline__ ushort_t f2bf(float v) {
  union { float f; unsigned int u; } c; c.f = v;
  unsigned int u = c.u;
  u += 0x7fffu + ((u >> 16) & 1u);
  return (ushort_t)(u >> 16);
}

__device__ __forceinline__ float bf2f(ushort_t u) {
  union { unsigned int u; float f; } c;
  c.u = ((unsigned int)u) << 16;
  return c.f;
}

__device__ __forceinline__ void gld_lds16(ushort_t* lds, const ushort_t* g) {
  __builtin_amdgcn_global_load_lds(
      (const __attribute__((address_space(1))) unsigned int*)g,
      (__attribute__((address_space(3))) unsigned int*)lds, 16, 0, 0);
}

// ---------------- prep: 6 weight transposes + x->bf16 + bias concat -------
// grid (128, 32, 8). z 0..3: Wq,Wk,Wv,Wo (bx<32); z=4: W1; z=5: W2;
// z=6: x fp32 -> xb bf16; z=7: concat biases.
__global__ __launch_bounds__(256) void prep_all(const float* __restrict__ s0,
                                                const float* __restrict__ s1,
                                                const float* __restrict__ s2,
                                                const float* __restrict__ s3,
                                                const float* __restrict__ s4,
                                                const float* __restrict__ s5,
                                                ushort_t* __restrict__ dqkv,
                                                ushort_t* __restrict__ dot,
                                                ushort_t* __restrict__ d1,
                                                ushort_t* __restrict__ d2,
                                                const float* __restrict__ x,
                                                ushort_t* __restrict__ xb,
                                                const float* __restrict__ ba,
                                                const float* __restrict__ bb,
                                                const float* __restrict__ bc,
                                                float* __restrict__ bqkv) {
  const int z = blockIdx.z;
  if (z == 6) {
    int i = (blockIdx.y * 128 + blockIdx.x) * 256 + threadIdx.x;  // < 1M float4s
    float4 v = ((const float4*)x)[i];
    ushort4 o;
    o.x = f2bf(v.x); o.y = f2bf(v.y); o.z = f2bf(v.z); o.w = f2bf(v.w);
    ((ushort4*)xb)[i] = o;
    return;
  }
  if (z == 7) {
    if (blockIdx.y != 0 || blockIdx.x >= 12) return;
    int i = blockIdx.x * 256 + threadIdx.x;
    float v = (i < 1024) ? ba[i] : (i < 2048 ? bb[i - 1024] : bc[i - 2048]);
    bqkv[i] = v;
    return;
  }
  __shared__ float t[32][33];
  const float* src;
  ushort_t* dst;
  int K, N, n0, k0;
  if (z < 4) {
    if (blockIdx.x >= 32) return;
    src = (z == 0) ? s0 : (z == 1) ? s1 : (z == 2) ? s2 : s3;
    dst = (z < 3) ? (dqkv + (size_t)z * 1024 * 1024) : dot;
    K = 1024; N = 1024; n0 = blockIdx.x * 32; k0 = blockIdx.y * 32;
  } else if (z == 4) {
    src = s4; dst = d1; K = 1024; N = 4096;
    n0 = blockIdx.x * 32; k0 = blockIdx.y * 32;
  } else {
    src = s5; dst = d2; K = 4096; N = 1024;
    n0 = blockIdx.y * 32; k0 = blockIdx.x * 32;
  }
  int c = threadIdx.x & 31, r0 = (threadIdx.x >> 5) * 4;
#pragma unroll
  for (int i = 0; i < 4; ++i)
    t[r0 + i][c] = src[(size_t)(k0 + r0 + i) * N + n0 + c];
  __syncthreads();
#pragma unroll
  for (int i = 0; i < 4; ++i)
    dst[(size_t)(n0 + r0 + i) * K + k0 + c] = f2bf(t[c][r0 + i]);
}

// ---------------- 128^2 MFMA GEMM (Wo split-K=2, bf16 partials) -----------
template<bool RELU, bool OUT_F32, bool OUT_BF16, int SPLITK>
__global__ __launch_bounds__(256) void gemm_mfma(const ushort_t* __restrict__ A,
                                                 const ushort_t* __restrict__ Bt,
                                                 const float* __restrict__ bias,
                                                 float* __restrict__ Cf,
                                                 ushort_t* __restrict__ Cb,
                                                 int M, int N, int K) {
  __shared__ __align__(16) ushort_t As[128 * 32];
  __shared__ __align__(16) ushort_t Bs[128 * 32];
  const int tid = threadIdx.x;
  const int w = tid >> 6, l = tid & 63;
  const int lane16 = l & 15, quad = l >> 4;
  const int wm = w & 1, wn = w >> 1;

  const int flat = blockIdx.y * gridDim.x + blockIdx.x;
  const int per = (gridDim.x * gridDim.y) >> 3;
  const int nf = (flat & 7) * per + (flat >> 3);
  const int bx = nf % gridDim.x;
  const int by = nf / gridDim.x;

  const int row0 = by * 128, col0 = bx * 128;
  const int z = (SPLITK > 1) ? blockIdx.z : 0;
  const int Kh = K / SPLITK;
  const int kbeg = z * Kh;

  const ushort_t* Ag = A + (size_t)row0 * K;
  const ushort_t* Bg = Bt + (size_t)col0 * K;

  f32x4 acc[4][4] = {};
  const int fr = tid >> 2;
  const int fc = (tid & 3) << 3;

  for (int kt = kbeg; kt < kbeg + Kh; kt += 32) {
#pragma unroll
    for (int rnd = 0; rnd < 2; ++rnd) {
      int r = fr + rnd * 64;
      ushort_t* ldsA = &As[(size_t)(rnd * 256 + w * 64) * 8];
      ushort_t* ldsB = &Bs[(size_t)(rnd * 256 + w * 64) * 8];
      gld_lds16(ldsA, Ag + (size_t)r * K + kt + fc);
      gld_lds16(ldsB, Bg + (size_t)r * K + kt + fc);
    }
    __syncthreads();
    short8 af[4], bfr[4];
#pragma unroll
    for (int i = 0; i < 4; ++i) {
      af[i]  = *(const short8*)&As[(wm * 64 + i * 16 + lane16) * 32 + quad * 8];
      bfr[i] = *(const short8*)&Bs[(wn * 64 + i * 16 + lane16) * 32 + quad * 8];
    }
#pragma unroll
    for (int mi = 0; mi < 4; ++mi)
#pragma unroll
      for (int ni = 0; ni < 4; ++ni)
        acc[mi][ni] = __builtin_amdgcn_mfma_f32_16x16x32_bf16(
            af[mi], bfr[ni], acc[mi][ni], 0, 0, 0);
    __syncthreads();
  }

  float* Cp = (SPLITK > 1 && OUT_F32) ? (Cf + (size_t)z * M * N) : Cf;
  ushort_t* Cbp = (SPLITK > 1 && OUT_BF16) ? (Cb + (size_t)z * M * N) : Cb;
#pragma unroll
  for (int mi = 0; mi < 4; ++mi) {
    int gr = row0 + wm * 64 + mi * 16 + quad * 4;
#pragma unroll
    for (int ni = 0; ni < 4; ++ni) {
      int gc = col0 + wn * 64 + ni * 16 + lane16;
      float bs = (SPLITK > 1) ? 0.0f : bias[gc];
#pragma unroll
      for (int r = 0; r < 4; ++r) {
        float v = acc[mi][ni][r] + bs;
        if (RELU) v = fmaxf(v, 0.0f);
        size_t idx = (size_t)(gr + r) * N + gc;
        if constexpr (OUT_F32) Cp[idx] = v;
        if constexpr (OUT_BF16) Cbp[idx] = f2bf(v);
      }
    }
  }
}

// ---------------- 256^2 2-barrier-per-tile counted-vmcnt GEMM -------------
// C = A(MxK,bf16) @ Bt(NxK,bf16)^T [+ bias] [, ReLU].
// PBF16: bf16 partials (no bias) to Cb + z*M*N; else bf16+bias to Cb.
// VT: blocks with col0>=2048 (QKV's V range) write TRANSPOSED to Vt
//     (each thread's r=0..3 are consecutive t -> one ushort4 store);
//     the qkvb V region is never read, so its write is skipped.
// Schedule per K-tile t (buf b=t&1, prefetch s=min(t+2,last)) — see r6:
//   reads+MFMA clusters, lgkm(0), BAR#1, STAGE(s)->buf[b], MFMA, vmcnt(8),
//   BAR#2. 2 barriers/tile; loads never drained to 0.
template<bool RELU, bool PBF16, int SPLITK, bool VT>
__global__ __launch_bounds__(512, 2) void gemm256(const ushort_t* __restrict__ A,
                                                  const ushort_t* __restrict__ Bt,
                                                  const float* __restrict__ bias,
                                                  ushort_t* __restrict__ Cb,
                                                  ushort_t* __restrict__ Vt,
                                                  int M, int N, int K) {
  __shared__ __align__(16) ushort_t sA[2][16384];
  __shared__ __align__(16) ushort_t sB[2][16384];
  const int tid = threadIdx.x;
  const int w = tid >> 6, l = tid & 63;
  const int lane16 = l & 15, quad = l >> 4;
  const int wm = w >> 2, wn = w & 3;

  const int gx = gridDim.x;
  const int flat = blockIdx.y * gx + blockIdx.x;
  const int per = (gx * gridDim.y) >> 3;
  const int nf = (flat & 7) * per + (flat >> 3);
  const int bx = nf % gx, by = nf / gx;
  const int row0 = by * 256, col0 = bx * 256;

  const int z = (SPLITK > 1) ? blockIdx.z : 0;
  const int Kh = K / SPLITK;
  const int kbeg = z * Kh;

  const ushort_t* Ag = A + (size_t)row0 * K + kbeg;
  const ushort_t* Bg = Bt + (size_t)col0 * K + kbeg;

  const int lr8 = l >> 3, lsl = l & 7;
  const size_t stg = (size_t)(w * 8 + lr8) * K + (size_t)((lsl ^ lr8) << 3);
  const int wslab = w * 512;

  const int rowA = (wm * 128 + lane16) * 64;
  const int rowB = (wn * 64 + lane16) * 64;
  const int sl0 = (quad ^ (lane16 & 7)) * 8;

  f32x4 acc[8][4] = {};
  short8 aA[4], aB[4], aC[4], b0[4], b1[4];

#define STAGE_A(bf, t, q) gld_lds16(&sA[bf][(q) * 4096 + wslab], \
    Ag + stg + (size_t)(q) * 64 * (size_t)K + (size_t)(t) * 64)
#define STAGE_B(bf, t, q) gld_lds16(&sB[bf][(q) * 4096 + wslab], \
    Bg + stg + (size_t)(q) * 64 * (size_t)K + (size_t)(t) * 64)
#define STAGE_ALL(bf, t) { \
    STAGE_A(bf, t, 0); STAGE_A(bf, t, 1); STAGE_A(bf, t, 2); STAGE_A(bf, t, 3); \
    STAGE_B(bf, t, 0); STAGE_B(bf, t, 1); STAGE_B(bf, t, 2); STAGE_B(bf, t, 3); }
#define LDAE(bf, mi, ks) (*(const short8*)&sA[bf][rowA + (mi) * 1024 + (sl0 ^ ((ks) * 32))])
#define LDBE(bf, ni, ks) (*(const short8*)&sB[bf][rowB + (ni) * 1024 + (sl0 ^ ((ks) * 32))])
#define LD_A4(dst, bf, mb, ks) { \
    dst[0] = LDAE(bf, (mb) + 0, ks); dst[1] = LDAE(bf, (mb) + 1, ks); \
    dst[2] = LDAE(bf, (mb) + 2, ks); dst[3] = LDAE(bf, (mb) + 3, ks); }
#define LD_B2(bf) { \
    b0[0] = LDBE(bf, 0, 0); b0[1] = LDBE(bf, 1, 0); \
    b0[2] = LDBE(bf, 2, 0); b0[3] = LDBE(bf, 3, 0); \
    b1[0] = LDBE(bf, 0, 1); b1[1] = LDBE(bf, 1, 1); \
    b1[2] = LDBE(bf, 2, 1); b1[3] = LDBE(bf, 3, 1); }
#define MFMA16(MB, AV, BV) { \
    _Pragma("unroll") for (int mi = 0; mi < 4; ++mi) { \
      _Pragma("unroll") for (int ni = 0; ni < 4; ++ni) \
        acc[(MB) + mi][ni] = __builtin_amdgcn_mfma_f32_16x16x32_bf16( \
            AV[mi], BV[ni], acc[(MB) + mi][ni], 0, 0, 0); \
    } }
#define BAR() __builtin_amdgcn_s_barrier()
#define WAIT_LGKM() asm volatile("s_waitcnt lgkmcnt(0)" ::: "memory")
#define WAIT_VM8() asm volatile("s_waitcnt vmcnt(8)" ::: "memory")

  // prologue: tile0 -> buf0, tile1 -> buf1 (8 loads each)
  STAGE_ALL(0, 0);
  STAGE_ALL(1, 1);
  WAIT_VM8();   // tile0's 8 landed; tile1's 8 in flight
  BAR();

  const int last = (Kh >> 6) - 1;
  const int nt = Kh >> 6;  // Kh multiple of 128 -> nt even, >= 2
  for (int t = 0; t < nt; ++t) {
    const int b = t & 1;
    int s = t + 2;
    if (s > last) s = last;

    LD_A4(aA, b, 0, 0); LD_A4(aB, b, 0, 1); LD_B2(b); LD_A4(aC, b, 4, 0);
    __builtin_amdgcn_s_setprio(1); MFMA16(0, aA, b0); __builtin_amdgcn_s_setprio(0);
    LD_A4(aA, b, 4, 1);
    __builtin_amdgcn_s_setprio(1);
    MFMA16(0, aB, b1);
    MFMA16(4, aC, b0);
    __builtin_amdgcn_s_setprio(0);
    WAIT_LGKM();               // WAR fence: this wave's buf[b] reads drained
    BAR();                     // all waves' reads of buf[b] complete
    STAGE_ALL(b, s);           // overwrite buf[b] with tile s
    __builtin_amdgcn_s_setprio(1); MFMA16(4, aA, b1); __builtin_amdgcn_s_setprio(0);
    WAIT_VM8();                // tile t+1 fully landed in buf[b^1]
    BAR();                     // publish
  }

#undef STAGE_A
#undef STAGE_B
#undef STAGE_ALL
#undef LDAE
#undef LDBE
#undef LD_A4
#undef LD_B2
#undef MFMA16
#undef BAR
#undef WAIT_LGKM
#undef WAIT_VM8

  if constexpr (PBF16) {
    ushort_t* Cp = Cb + (size_t)z * M * N;
#pragma unroll
    for (int mi = 0; mi < 8; ++mi) {
      const int gr = row0 + wm * 128 + mi * 16 + quad * 4;
#pragma unroll
      for (int ni = 0; ni < 4; ++ni) {
        const int gc = col0 + wn * 64 + ni * 16 + lane16;
#pragma unroll
        for (int r = 0; r < 4; ++r)
          Cp[(size_t)(gr + r) * N + gc] = f2bf(acc[mi][ni][r]);
      }
    }
  } else if (VT && col0 >= 2048) {
    // V columns: write transposed to Vt[(n*16+h)*64 + hs][t], t = gr&1023.
    // r=0..3 are consecutive t -> one ushort4 store per fragment row-quad.
#pragma unroll
    for (int mi = 0; mi < 8; ++mi) {
      const int gr = row0 + wm * 128 + mi * 16 + quad * 4;
      const int nbt = gr >> 10;        // batch
      const int tt = gr & 1023;        // seq position (4-aligned)
#pragma unroll
      for (int ni = 0; ni < 4; ++ni) {
        const int gc = col0 + wn * 64 + ni * 16 + lane16;
        const int d = gc - 2048;       // h*64 + hs
        const float bs = bias[gc];
        ushort4 o;
        o.x = f2bf(acc[mi][ni][0] + bs);
        o.y = f2bf(acc[mi][ni][1] + bs);
        o.z = f2bf(acc[mi][ni][2] + bs);
        o.w = f2bf(acc[mi][ni][3] + bs);
        *(ushort4*)&Vt[(size_t)((nbt << 4) + (d >> 6)) * 64 * SEQ +
                       (size_t)(d & 63) * SEQ + tt] = o;
      }
    }
  } else {
#pragma unroll
    for (int mi = 0; mi < 8; ++mi) {
      const int gr = row0 + wm * 128 + mi * 16 + quad * 4;
#pragma unroll
      for (int ni = 0; ni < 4; ++ni) {
        const int gc = col0 + wn * 64 + ni * 16 + lane16;
        const float bs = bias[gc];
#pragma unroll
        for (int r = 0; r < 4; ++r) {
          float v = acc[mi][ni][r] + bs;
          if (RELU) v = fmaxf(v, 0.0f);
          Cb[(size_t)(gr + r) * N + gc] = f2bf(v);
        }
      }
    }
  }
}

// ---------------- MFMA flash attention v2 (no-max softmax) ----------------
__global__ __launch_bounds__(256) void attn_mfma(const ushort_t* __restrict__ QKVb,
                                                 const ushort_t* __restrict__ Vtb,
                                                 ushort_t* __restrict__ Ob) {
  const int nh = blockIdx.x, qt = blockIdx.y;
  const int n = nh >> 4, h = nh & 15;
  const int tid = threadIdx.x;
  const int w = tid >> 6, l = tid & 63;
  const int lane16 = l & 15, quad = l >> 4;

  __shared__ __align__(16) ushort_t Ks[2][4096];
  __shared__ __align__(16) ushort_t Vs[2][4096];
  __shared__ __align__(16) ushort_t Ps[2][128][PD];

  const int q0 = qt * 128;

  short8 aq[2][2];
#pragma unroll
  for (int qf = 0; qf < 2; ++qf)
#pragma unroll
    for (int ks = 0; ks < 2; ++ks)
      aq[qf][ks] = *(const short8*)(QKVb +
          (size_t)(n * SEQ + q0 + w * 32 + qf * 16 + lane16) * 3072 +
          h * 64 + ks * 32 + quad * 8);

  const int lr8 = l >> 3;
  const int swsl = ((l & 7) ^ lr8) << 3;
  const int ldst = (w * 16) * 64;
  const int rx = lane16 & 7;

  float l_i[2][4] = {{0.f,0.f,0.f,0.f},{0.f,0.f,0.f,0.f}};
  f32x4 o_acc[2][4] = {};

#define STAGE_K(bf, kt, i) gld_lds16(&Ks[bf][ldst + (i) * 512], \
    QKVb + (size_t)(n * SEQ + (kt) * 64 + w * 16 + (i) * 8 + lr8) * 3072 + \
    1024 + h * 64 + swsl)
#define STAGE_V(bf, kt, i) gld_lds16(&Vs[bf][ldst + (i) * 512], \
    Vtb + (size_t)(nh * 64 + w * 16 + (i) * 8 + lr8) * SEQ + (kt) * 64 + swsl)

  STAGE_K(0, 0, 0); STAGE_K(0, 0, 1);
  STAGE_V(0, 0, 0); STAGE_V(0, 0, 1);

  for (int kt = 0; kt < 16; ++kt) {
    const int b = kt & 1;
    const int nx = (kt < 15) ? kt + 1 : 15;
    STAGE_K(b ^ 1, nx, 0); STAGE_K(b ^ 1, nx, 1);
    STAGE_V(b ^ 1, nx, 0); STAGE_V(b ^ 1, nx, 1);
    asm volatile("s_waitcnt vmcnt(4)" ::: "memory");
    __builtin_amdgcn_s_barrier();

    f32x4 s[2][4] = {};
    __builtin_amdgcn_s_setprio(1);
#pragma unroll
    for (int ks = 0; ks < 2; ++ks)
#pragma unroll
      for (int ni = 0; ni < 4; ++ni) {
        const int row = ni * 16 + lane16;
        short8 bk = *(const short8*)&Ks[b][row * 64 + (((ks * 4 + quad) ^ rx) << 3)];
        s[0][ni] = __builtin_amdgcn_mfma_f32_16x16x32_bf16(aq[0][ks], bk, s[0][ni], 0, 0, 0);
        s[1][ni] = __builtin_amdgcn_mfma_f32_16x16x32_bf16(aq[1][ks], bk, s[1][ni], 0, 0, 0);
      }
    __builtin_amdgcn_s_setprio(0);

#pragma unroll
    for (int qf = 0; qf < 2; ++qf)
#pragma unroll
      for (int ni = 0; ni < 4; ++ni)
#pragma unroll
        for (int r = 0; r < 4; ++r) {
          float p = __expf(s[qf][ni][r] * 0.125f);
          l_i[qf][r] += p;
          Ps[ni >> 1][w * 32 + qf * 16 + quad * 4 + r][(ni & 1) * 16 + lane16] = f2bf(p);
        }

    __builtin_amdgcn_s_setprio(1);
#pragma unroll
    for (int ks = 0; ks < 2; ++ks) {
      short8 ap0 = *(const short8*)&Ps[ks][w * 32 + lane16][quad * 8];
      short8 ap1 = *(const short8*)&Ps[ks][w * 32 + 16 + lane16][quad * 8];
#pragma unroll
      for (int nd = 0; nd < 4; ++nd) {
        const int row = nd * 16 + lane16;
        short8 bv = *(const short8*)&Vs[b][row * 64 + (((ks * 4 + quad) ^ rx) << 3)];
        o_acc[0][nd] = __builtin_amdgcn_mfma_f32_16x16x32_bf16(ap0, bv, o_acc[0][nd], 0, 0, 0);
        o_acc[1][nd] = __builtin_amdgcn_mfma_f32_16x16x32_bf16(ap1, bv, o_acc[1][nd], 0, 0, 0);
      }
    }
    __builtin_amdgcn_s_setprio(0);
    __builtin_amdgcn_s_barrier();
  }

#undef STAGE_K
#undef STAGE_V

#pragma unroll
  for (int qf = 0; qf < 2; ++qf)
#pragma unroll
    for (int r = 0; r < 4; ++r) {
      float li = l_i[qf][r];
#pragma unroll
      for (int m = 1; m <= 8; m <<= 1)
        li += __shfl_xor(li, m, 64);
      const float inv = 1.0f / li;
      const int gq = n * SEQ + q0 + w * 32 + qf * 16 + quad * 4 + r;
#pragma unroll
      for (int nd = 0; nd < 4; ++nd)
        Ob[(size_t)gq * HDIM + h * 64 + nd * 16 + lane16] = f2bf(o_acc[qf][nd][r] * inv);
    }
}

// -- LayerNorm(sum of 2 BF16 partials + bias) * g + b + resid; bf16 copy --
template<bool WB>
__global__ __launch_bounds__(256) void ln_sum2b_kernel(const ushort_t* __restrict__ pw,
                                                       const float* __restrict__ bias,
                                                       const float* __restrict__ resid,
                                                       const float* __restrict__ g,
                                                       const float* __restrict__ b,
                                                       float* __restrict__ out,
                                                       ushort_t* __restrict__ outb) {
  const int row = blockIdx.x;
  const int tid = threadIdx.x;
  const size_t base = (size_t)row * HDIM;
  const int c0 = tid * 4;
  const size_t MN = (size_t)ROWS * HDIM;

  float4 bi = *(const float4*)&bias[c0];
  float v[4] = {bi.x, bi.y, bi.z, bi.w};
#pragma unroll
  for (int zz = 0; zz < 2; ++zz) {
    ushort4 u = *(const ushort4*)&pw[zz * MN + base + c0];
    v[0] += bf2f(u.x); v[1] += bf2f(u.y); v[2] += bf2f(u.z); v[3] += bf2f(u.w);
  }
  float s = v[0] + v[1] + v[2] + v[3];
  float sq = v[0]*v[0] + v[1]*v[1] + v[2]*v[2] + v[3]*v[3];
  for (int off = 32; off; off >>= 1) {
    s += __shfl_down(s, off, 64);
    sq += __shfl_down(sq, off, 64);
  }
  __shared__ float redA[4], redB[4], bc2[2];
  const int wave = tid >> 6;
  if ((tid & 63) == 0) { redA[wave] = s; redB[wave] = sq; }
  __syncthreads();
  if (tid == 0) {
    float S = redA[0] + redA[1] + redA[2] + redA[3];
    float Q = redB[0] + redB[1] + redB[2] + redB[3];
    float mean = S * (1.0f / HDIM);
    bc2[0] = mean;
    bc2[1] = rsqrtf(Q * (1.0f / HDIM) - mean * mean + 1e-5f);
  }
  __syncthreads();
  const float mean = bc2[0], rstd = bc2[1];
  float4 gg = *(const float4*)&g[c0];
  float4 bb = *(const float4*)&b[c0];
  float4 rr = *(const float4*)&resid[base + c0];
  float4 o;
  o.x = (v[0] - mean) * rstd * gg.x + bb.x + rr.x;
  o.y = (v[1] - mean) * rstd * gg.y + bb.y + rr.y;
  o.z = (v[2] - mean) * rstd * gg.z + bb.z + rr.z;
  o.w = (v[3] - mean) * rstd * gg.w + bb.w + rr.w;
  *(float4*)&out[base + c0] = o;
  if constexpr (WB) {
    ushort4 ob;
    ob.x = f2bf(o.x); ob.y = f2bf(o.y); ob.z = f2bf(o.z); ob.w = f2bf(o.w);
    *(ushort4*)&outb[base + c0] = ob;
  }
}

// -------- LayerNorm(sum of 4 BF16 partials + bias) * g + b + resid --------
__global__ __launch_bounds__(256) void ln_sum4b_kernel(const ushort_t* __restrict__ pb,
                                                       const float* __restrict__ bias,
                                                       const float* __restrict__ resid,
                                                       const float* __restrict__ g,
                                                       const float* __restrict__ b,
                                                       float* __restrict__ out) {
  const int row = blockIdx.x;
  const int tid = threadIdx.x;
  const size_t base = (size_t)row * HDIM;
  const int c0 = tid * 4;
  const size_t MN = (size_t)ROWS * HDIM;

  float4 bi = *(const float4*)&bias[c0];
  float v[4] = {bi.x, bi.y, bi.z, bi.w};
#pragma unroll
  for (int zz = 0; zz < 4; ++zz) {
    ushort4 u = *(const ushort4*)&pb[zz * MN + base + c0];
    v[0] += bf2f(u.x); v[1] += bf2f(u.y); v[2] += bf2f(u.z); v[3] += bf2f(u.w);
  }
  float s = v[0] + v[1] + v[2] + v[3];
  float sq = v[0]*v[0] + v[1]*v[1] + v[2]*v[2] + v[3]*v[3];
  for (int off = 32; off; off >>= 1) {
    s += __shfl_down(s, off, 64);
    sq += __shfl_down(sq, off, 64);
  }
  __shared__ float redA[4], redB[4], bc2[2];
  const int wave = tid >> 6;
  if ((tid & 63) == 0) { redA[wave] = s; redB[wave] = sq; }
  __syncthreads();
  if (tid == 0) {
    float S = redA[0] + redA[1] + redA[2] + redA[3];
    float Q = redB[0] + redB[1] + redB[2] + redB[3];
    float mean = S * (1.0f / HDIM);
    bc2[0] = mean;
    bc2[1] = rsqrtf(Q * (1.0f / HDIM) - mean * mean + 1e-5f);
  }
  __syncthreads();
  const float mean = bc2[0], rstd = bc2[1];
  float4 gg = *(const float4*)&g[c0];
  float4 bb = *(const float4*)&b[c0];
  float4 rr = *(const float4*)&resid[base + c0];
  float4 o;
  o.x = (v[0] - mean) * rstd * gg.x + bb.x + rr.x;
  o.y = (v[1] - mean) * rstd * gg.y + bb.y + rr.y;
  o.z = (v[2] - mean) * rstd * gg.z + bb.z + rr.z;
  o.w = (v[3] - mean) * rstd * gg.w + bb.w + rr.w;
  *(float4*)&out[base + c0] = o;
}

extern "C" void kernel_launch(void* const* d_in, const int* in_sizes, int n_in,
                              void* d_out, int out_size, void* d_ws, size_t ws_size,
                              hipStream_t stream) {
  const float* x    = (const float*)d_in[0];
  const float* Wq   = (const float*)d_in[2];
  const float* bq   = (const float*)d_in[3];
  const float* Wk   = (const float*)d_in[4];
  const float* bk   = (const float*)d_in[5];
  const float* Wv   = (const float*)d_in[6];
  const float* bv   = (const float*)d_in[7];
  const float* Wo   = (const float*)d_in[8];
  const float* bo   = (const float*)d_in[9];
  const float* g1   = (const float*)d_in[10];
  const float* b1n  = (const float*)d_in[11];
  const float* W1   = (const float*)d_in[12];
  const float* b1   = (const float*)d_in[13];
  const float* W2   = (const float*)d_in[14];
  const float* b2   = (const float*)d_in[15];
  const float* g2   = (const float*)d_in[16];
  const float* b2n  = (const float*)d_in[17];

  char* ws = (char*)d_ws;
  const size_t MB = 1024 * 1024;
  ushort_t* qkvb   = (ushort_t*)(ws + 0);         // 24 MB (dead after attn)
  ushort_t* pw     = (ushort_t*)(ws + 0);         // Wo bf16 partials 2x8MB
  ushort_t* pb     = (ushort_t*)(ws + 0);         // FFN2 bf16 partials 4x8MB
  ushort_t* vtb    = (ushort_t*)(ws + 24 * MB);   // 8 MB (QKV epi -> attn)
  float*    x1     = (float*)(ws + 32 * MB);      // 16 MB
  ushort_t* x1b    = (ushort_t*)(ws + 48 * MB);   // 8 MB
  ushort_t* ctxb   = (ushort_t*)(ws + 56 * MB);   // 8 MB
  ushort_t* hb     = (ushort_t*)(ws + 64 * MB);   // 32 MB
  ushort_t* xb     = (ushort_t*)(ws + 64 * MB);   // reuse hb region pre-FFN1
  ushort_t* Wqkvt  = (ushort_t*)(ws + 96 * MB);   // 6 MB
  ushort_t* Wot    = (ushort_t*)(ws + 102 * MB);  // 2 MB
  ushort_t* W1t    = (ushort_t*)(ws + 104 * MB);  // 8 MB
  ushort_t* W2t    = (ushort_t*)(ws + 112 * MB);  // 8 MB
  float*    bqkv   = (float*)(ws + 120 * MB);     // 12 KB

  dim3 blk(256);

  // weights transpose + x->bf16 + bias concat, one dispatch
  prep_all<<<dim3(128, 32, 8), blk, 0, stream>>>(Wq, Wk, Wv, Wo, W1, W2,
                                                 Wqkvt, Wot, W1t, W2t,
                                                 x, xb, bq, bk, bv, bqkv);

  // fused QKV GEMM -> qkvb (Q,K) + vtb (V transposed, fused epilogue)
  gemm256<false, false, 1, true><<<dim3(3072 / 256, ROWS / 256), dim3(512), 0, stream>>>(
      xb, Wqkvt, bqkv, qkvb, vtb, ROWS, 3072, HDIM);

  // attention v2: grid (64, 8), QBLK=128
  attn_mfma<<<dim3(NBATCH * NHEAD, SEQ / 128), blk, 0, stream>>>(qkvb, vtb, ctxb);

  // ctx @ Wo, split-K=2 -> bf16 partials pw[0..2); bias folded into LN1
  gemm_mfma<false, false, true, 2><<<dim3(HDIM / 128, ROWS / 128, 2), blk, 0, stream>>>(
      ctxb, Wot, nullptr, nullptr, pw, ROWS, HDIM, HDIM);

  ln_sum2b_kernel<true><<<dim3(ROWS), blk, 0, stream>>>(pw, bo, x, g1, b1n, x1, x1b);

  // FFN1 + ReLU -> hb bf16 (256^2 2-bar/tile; grid 16x16 = 256 blocks)
  gemm256<true, false, 1, false><<<dim3(FDIM / 256, ROWS / 256), dim3(512), 0, stream>>>(
      x1b, W1t, b1, hb, nullptr, ROWS, FDIM, HDIM);

  // FFN2: 256^2 2-bar/tile split-K=4 (grid 4x16x4 = 256 blocks, Kh=1024);
  // bf16 partials to pb[0..4) (4x8MB at ws[0,32M)); bias folded into LN2.
  gemm256<false, true, 4, false><<<dim3(HDIM / 256, ROWS / 256, 4), dim3(512), 0, stream>>>(
      hb, W2t, nullptr, pb, nullptr, ROWS, HDIM, FDIM);

  ln_sum4b_kernel<<<dim3(ROWS), blk, 0, stream>>>(pb, b2, x1, g2, b2n, (float*)d_out);
}